// Round 1
// baseline (5909.527 us; speedup 1.0000x reference)
//
#include <hip/hip_runtime.h>
#include <math.h>

#define E 256
#define SEQ 32
#define FF 1024
#define NEG_MASK -10000.0f

// ---------- helpers ----------
__device__ __forceinline__ float block_sum256(float v, float* tmp4) {
  #pragma unroll
  for (int o = 32; o > 0; o >>= 1) v += __shfl_down(v, o);
  int wid = threadIdx.x >> 6, lane = threadIdx.x & 63;
  if (lane == 0) tmp4[wid] = v;
  __syncthreads();
  float r = tmp4[0] + tmp4[1] + tmp4[2] + tmp4[3];
  __syncthreads();
  return r;
}

// ---------- sparse prop + W_d + LN (one row of output per batch) ----------
// t_in[n] = 0.5*emb[b,n] + snq[b,n] ; t1 = U t_in + 0.1 t_in ; t2 = U t1 + 0.1 t_in
// out[b] = LN(t2[row] @ Wd + bd)
__global__ __launch_bounds__(256) void prop_ln_kernel(
    const float* __restrict__ emb, const float* snq, int snq_off,
    const float* __restrict__ op, const float* __restrict__ Wd,
    const float* __restrict__ bd, const float* __restrict__ g,
    const float* __restrict__ bvec, float* __restrict__ outp, int row) {
  __shared__ float wv[64];
  __shared__ int gi[64];
  __shared__ float s1[16 * E];
  __shared__ float s2[16 * E];
  __shared__ float t2row[E];
  __shared__ float tmp4[4];
  int b = blockIdx.x, e = threadIdx.x;
  if (e < 64) {
    wv[e] = op[(b * 64 + e) * 2 + 1];
    gi[e] = (int)op[(b * 64 + e) * 2 + 0];
  }
  for (int gg = 0; gg < 16; ++gg) { s1[gg * E + e] = 0.f; s2[gg * E + e] = 0.f; }
  __syncthreads();
  float t0r = 0.f;
  for (int n = 0; n < 64; ++n) {
    float t0 = 0.5f * emb[(b * 64 + n) * E + e];
    if (snq) t0 += snq[((size_t)(b * 64 + n) * 2 + snq_off) * E + e];
    if (n == row) t0r = t0;
    s1[gi[n] * E + e] += wv[n] * t0;  // column-private: no races
  }
  for (int n = 0; n < 64; ++n) {
    float t0 = 0.5f * emb[(b * 64 + n) * E + e];
    if (snq) t0 += snq[((size_t)(b * 64 + n) * 2 + snq_off) * E + e];
    float t1 = wv[n] * s1[gi[n] * E + e] + 0.1f * t0;
    s2[gi[n] * E + e] += wv[n] * t1;
  }
  float t2 = wv[row] * s2[gi[row] * E + e] + 0.1f * t0r;
  t2row[e] = t2;
  __syncthreads();
  float y = bd[e];
  for (int k = 0; k < E; ++k) y = fmaf(t2row[k], Wd[k * E + e], y);
  float ssum = block_sum256(y, tmp4);
  float qsum = block_sum256(y * y, tmp4);
  float m = ssum * (1.f / E);
  float var = qsum * (1.f / E) - m * m;
  outp[b * E + e] = (y - m) * rsqrtf(var + 1e-12f) * g[e] + bvec[e];
}

// ---------- fused Q/K/V projection (32 rows per block) ----------
__global__ __launch_bounds__(256) void qkv_kernel(
    const float* __restrict__ A,
    const float* __restrict__ Wq, const float* __restrict__ bq,
    const float* __restrict__ Wk, const float* __restrict__ bk,
    const float* __restrict__ Wv, const float* __restrict__ bv,
    float* __restrict__ Q, float* __restrict__ K, float* __restrict__ V) {
  __shared__ float aT[32][E];
  int row0 = blockIdx.x * 32, t = threadIdx.x;
  for (int r = 0; r < 32; ++r) aT[r][t] = A[(size_t)(row0 + r) * E + t];
  __syncthreads();
  float accq[32], acck[32], accv[32];
  float bqv = bq[t], bkv = bk[t], bvv = bv[t];
  #pragma unroll
  for (int r = 0; r < 32; ++r) { accq[r] = bqv; acck[r] = bkv; accv[r] = bvv; }
  for (int e0 = 0; e0 < E; e0 += 4) {
    float wq0 = Wq[(e0+0)*E+t], wq1 = Wq[(e0+1)*E+t], wq2 = Wq[(e0+2)*E+t], wq3 = Wq[(e0+3)*E+t];
    float wk0 = Wk[(e0+0)*E+t], wk1 = Wk[(e0+1)*E+t], wk2 = Wk[(e0+2)*E+t], wk3 = Wk[(e0+3)*E+t];
    float wv0 = Wv[(e0+0)*E+t], wv1 = Wv[(e0+1)*E+t], wv2 = Wv[(e0+2)*E+t], wv3 = Wv[(e0+3)*E+t];
    #pragma unroll
    for (int r = 0; r < 32; ++r) {
      float4 a4 = *(const float4*)&aT[r][e0];
      accq[r] = fmaf(a4.x, wq0, fmaf(a4.y, wq1, fmaf(a4.z, wq2, fmaf(a4.w, wq3, accq[r]))));
      acck[r] = fmaf(a4.x, wk0, fmaf(a4.y, wk1, fmaf(a4.z, wk2, fmaf(a4.w, wk3, acck[r]))));
      accv[r] = fmaf(a4.x, wv0, fmaf(a4.y, wv1, fmaf(a4.z, wv2, fmaf(a4.w, wv3, accv[r]))));
    }
  }
  for (int r = 0; r < 32; ++r) {
    size_t o = (size_t)(row0 + r) * E + t;
    Q[o] = accq[r]; K[o] = acck[r]; V[o] = accv[r];
  }
}

// ---------- attention: one block per (sequence, head). CTX may alias Q. ----------
__global__ __launch_bounds__(256) void attn_kernel(
    const float* Q, const float* K, const float* V, float* CTX,
    const float* __restrict__ mask, int mask_stride, int set4) {
  int a = blockIdx.x, h = blockIdx.y, t = threadIdx.x;
  __shared__ float qs[32][65], ks[32][65], vs[32][65];
  __shared__ float pr[32][33];
  size_t base = (size_t)a * (SEQ * E) + h * 64;
  for (int i = 0; i < 8; ++i) {
    int p = i * 256 + t; int s = p >> 6, d = p & 63;
    qs[s][d] = Q[base + s * E + d];
    ks[s][d] = K[base + s * E + d];
    vs[s][d] = V[base + s * E + d];
  }
  __syncthreads();
  for (int i = 0; i < 4; ++i) {
    int p = i * 256 + t; int s = p >> 5, tt = p & 31;
    float acc = 0.f;
    #pragma unroll
    for (int d = 0; d < 64; ++d) acc = fmaf(qs[s][d], ks[tt][d], acc);
    float mv = mask[(size_t)a * mask_stride + tt];
    if (set4 && tt < 4) mv = NEG_MASK;
    pr[s][tt] = acc * 0.125f + mv;
  }
  __syncthreads();
  int rrow = t >> 3, l = t & 7;
  float vals[4];
  float mx = -1e30f;
  #pragma unroll
  for (int ii = 0; ii < 4; ++ii) { vals[ii] = pr[rrow][l + ii * 8]; mx = fmaxf(mx, vals[ii]); }
  mx = fmaxf(mx, __shfl_xor(mx, 1));
  mx = fmaxf(mx, __shfl_xor(mx, 2));
  mx = fmaxf(mx, __shfl_xor(mx, 4));
  float se = 0.f;
  #pragma unroll
  for (int ii = 0; ii < 4; ++ii) { vals[ii] = expf(vals[ii] - mx); se += vals[ii]; }
  se += __shfl_xor(se, 1); se += __shfl_xor(se, 2); se += __shfl_xor(se, 4);
  float inv = 1.f / se;
  #pragma unroll
  for (int ii = 0; ii < 4; ++ii) pr[rrow][l + ii * 8] = vals[ii] * inv;
  __syncthreads();
  for (int i = 0; i < 8; ++i) {
    int p = i * 256 + t; int s = p >> 6, d = p & 63;
    float acc = 0.f;
    #pragma unroll
    for (int tt = 0; tt < SEQ; ++tt) acc = fmaf(pr[s][tt], vs[tt][d], acc);
    CTX[base + s * E + d] = acc;
  }
}

// ---------- GEMM(K=256) + bias + residual + LayerNorm ----------
__global__ __launch_bounds__(256) void ln_gemm_kernel(
    const float* __restrict__ A, const float* __restrict__ W,
    const float* __restrict__ bias, const float* __restrict__ Res,
    const float* __restrict__ g, const float* __restrict__ bvec,
    float* __restrict__ OUT) {
  __shared__ float aT[32][E];
  __shared__ float prs[32][4], prq[32][4];
  int row0 = blockIdx.x * 32, t = threadIdx.x;
  for (int r = 0; r < 32; ++r) aT[r][t] = A[(size_t)(row0 + r) * E + t];
  __syncthreads();
  float acc[32];
  float bv = bias[t];
  #pragma unroll
  for (int r = 0; r < 32; ++r) acc[r] = bv;
  for (int e0 = 0; e0 < E; e0 += 4) {
    float w0 = W[(e0+0)*E+t], w1 = W[(e0+1)*E+t], w2 = W[(e0+2)*E+t], w3 = W[(e0+3)*E+t];
    #pragma unroll
    for (int r = 0; r < 32; ++r) {
      float4 a4 = *(const float4*)&aT[r][e0];
      acc[r] = fmaf(a4.x, w0, fmaf(a4.y, w1, fmaf(a4.z, w2, fmaf(a4.w, w3, acc[r]))));
    }
  }
  #pragma unroll
  for (int r = 0; r < 32; ++r) acc[r] += Res[(size_t)(row0 + r) * E + t];
  int wid = t >> 6, lane = t & 63;
  for (int r = 0; r < 32; ++r) {
    float s = acc[r], q = acc[r] * acc[r];
    #pragma unroll
    for (int o = 32; o > 0; o >>= 1) { s += __shfl_down(s, o); q += __shfl_down(q, o); }
    if (lane == 0) { prs[r][wid] = s; prq[r][wid] = q; }
  }
  __syncthreads();
  #pragma unroll
  for (int r = 0; r < 32; ++r) {
    float Sv = prs[r][0] + prs[r][1] + prs[r][2] + prs[r][3];
    float Qv = prq[r][0] + prq[r][1] + prq[r][2] + prq[r][3];
    float m = Sv * (1.f / E), var = Qv * (1.f / E) - m * m;
    OUT[(size_t)(row0 + r) * E + t] = (acc[r] - m) * rsqrtf(var + 1e-12f) * g[t] + bvec[t];
  }
}

// ---------- fused FFN: LN(gelu(A@Wi+bi)@Wf + bf + A). Compact output options. ----------
__global__ __launch_bounds__(256) void ffn_kernel(
    const float* __restrict__ A,
    const float* __restrict__ Wi, const float* __restrict__ bi,
    const float* __restrict__ Wf, const float* __restrict__ bf,
    const float* __restrict__ g, const float* __restrict__ bvec,
    float* out_full, float* out01, float* out_n0, int seq_base) {
  __shared__ float aT[32][E];
  __shared__ float fT[32][E];
  __shared__ float prs[32][4], prq[32][4];
  int a = seq_base + blockIdx.x;
  int row0 = blockIdx.x * 32, t = threadIdx.x;
  for (int r = 0; r < 32; ++r) aT[r][t] = A[(size_t)(row0 + r) * E + t];
  __syncthreads();
  float acch[32];
  float bfv = bf[t];
  #pragma unroll
  for (int r = 0; r < 32; ++r) acch[r] = bfv + aT[r][t];  // bias + residual
  for (int c = 0; c < 4; ++c) {
    int j = c * 256 + t;
    float accf[32];
    float biv = bi[j];
    #pragma unroll
    for (int r = 0; r < 32; ++r) accf[r] = biv;
    for (int e0 = 0; e0 < E; e0 += 4) {
      float w0 = Wi[(e0+0)*FF+j], w1 = Wi[(e0+1)*FF+j], w2 = Wi[(e0+2)*FF+j], w3 = Wi[(e0+3)*FF+j];
      #pragma unroll
      for (int r = 0; r < 32; ++r) {
        float4 a4 = *(const float4*)&aT[r][e0];
        accf[r] = fmaf(a4.x, w0, fmaf(a4.y, w1, fmaf(a4.z, w2, fmaf(a4.w, w3, accf[r]))));
      }
    }
    if (c > 0) __syncthreads();  // previous phase-2 readers done before fT overwrite
    #pragma unroll
    for (int r = 0; r < 32; ++r) {
      float x = accf[r];
      fT[r][t] = 0.5f * x * (1.f + erff(x * 0.70710678118654752f));
    }
    __syncthreads();
    for (int j0 = 0; j0 < 256; j0 += 4) {
      float w0 = Wf[(c*256+j0+0)*E+t], w1 = Wf[(c*256+j0+1)*E+t],
            w2 = Wf[(c*256+j0+2)*E+t], w3 = Wf[(c*256+j0+3)*E+t];
      #pragma unroll
      for (int r = 0; r < 32; ++r) {
        float4 f4 = *(const float4*)&fT[r][j0];
        acch[r] = fmaf(f4.x, w0, fmaf(f4.y, w1, fmaf(f4.z, w2, fmaf(f4.w, w3, acch[r]))));
      }
    }
  }
  int wid = t >> 6, lane = t & 63;
  for (int r = 0; r < 32; ++r) {
    float s = acch[r], q = acch[r] * acch[r];
    #pragma unroll
    for (int o = 32; o > 0; o >>= 1) { s += __shfl_down(s, o); q += __shfl_down(q, o); }
    if (lane == 0) { prs[r][wid] = s; prq[r][wid] = q; }
  }
  __syncthreads();
  int n = a & 63;
  #pragma unroll
  for (int r = 0; r < 32; ++r) {
    float Sv = prs[r][0] + prs[r][1] + prs[r][2] + prs[r][3];
    float Qv = prq[r][0] + prq[r][1] + prq[r][2] + prq[r][3];
    float m = Sv * (1.f / E), var = Qv * (1.f / E) - m * m;
    float val = (acch[r] - m) * rsqrtf(var + 1e-12f) * g[t] + bvec[t];
    if (out_full) out_full[((size_t)a * SEQ + r) * E + t] = val;
    if (out01 && r < 2) out01[((size_t)a * 2 + r) * E + t] = val;
    if (out_n0 && n == 0) out_n0[((size_t)(a >> 6) * SEQ + r) * E + t] = val;
  }
}

// ---------- agg: l2norm(relu([l2norm(hrow4), p1, p2] @ Wagg + bagg)) ----------
__global__ __launch_bounds__(256) void agg_kernel(
    const float* __restrict__ hbase, int hstride,
    const float* __restrict__ p1, const float* __restrict__ p2,
    const float* __restrict__ Wagg, const float* __restrict__ bagg,
    float* __restrict__ outp) {
  __shared__ float pv[768];
  __shared__ float tmp4[4];
  int b = blockIdx.x, t = threadIdx.x;
  float x = hbase[(size_t)b * hstride + 4 * E + t];
  float n2 = block_sum256(x * x, tmp4);
  pv[t] = x / fmaxf(sqrtf(n2), 1e-12f);
  pv[256 + t] = p1[b * E + t];
  pv[512 + t] = p2[b * E + t];
  __syncthreads();
  float y = bagg[t];
  for (int u = 0; u < 768; ++u) y = fmaf(pv[u], Wagg[u * E + t], y);
  y = fmaxf(y, 0.f);
  float n3 = block_sum256(y * y, tmp4);
  outp[b * E + t] = y / fmaxf(sqrtf(n3), 1e-12f);
}

// ---------- build iter-1 input for n==0 sequences ----------
__global__ __launch_bounds__(256) void build_h2_kernel(
    const float* __restrict__ qe, const float* __restrict__ ke,
    const float* __restrict__ de, const float* __restrict__ ce,
    const float* __restrict__ agg0, const float* __restrict__ h1n0,
    float* __restrict__ h2in) {
  int b = blockIdx.x, t = threadIdx.x;
  size_t eb = (size_t)(b * 64) * E + t;  // embedding at (b, n=0)
  size_t ob = (size_t)b * (SEQ * E);
  h2in[ob + 0 * E + t] = qe[eb];
  h2in[ob + 1 * E + t] = ke[eb];
  h2in[ob + 2 * E + t] = de[eb];
  h2in[ob + 3 * E + t] = ce[eb];
  h2in[ob + 4 * E + t] = agg0[b * E + t];
  for (int s = 5; s < SEQ; ++s) h2in[ob + s * E + t] = h1n0[ob + s * E + t];
}

// ---------- final output ----------
__global__ __launch_bounds__(256) void out_kernel(
    const float* __restrict__ h1n0, const float* __restrict__ agg0,
    const float* __restrict__ h2, const float* __restrict__ agg1,
    float* __restrict__ outp) {
  int b = blockIdx.x, t = threadIdx.x;
  size_t ob = (size_t)b * (SEQ * E);
  float s1v = agg0[b * E + t];
  float s2v = agg1[b * E + t];
  for (int s = 5; s < SEQ; ++s) { s1v += h1n0[ob + s * E + t]; s2v += h2[ob + s * E + t]; }
  outp[b * E + t] = 0.5f * (s1v + s2v) * (1.f / 28.f);
}

extern "C" void kernel_launch(void* const* d_in, const int* in_sizes, int n_in,
                              void* d_out, int out_size, void* d_ws, size_t ws_size,
                              hipStream_t stream) {
  (void)in_sizes; (void)n_in; (void)out_size;
  const float* hidden = (const float*)d_in[1];
  const float* amask  = (const float*)d_in[2];
  const float* qemb   = (const float*)d_in[3];
  const float* kemb   = (const float*)d_in[4];
  const float* demb   = (const float*)d_in[5];
  const float* cemb   = (const float*)d_in[6];
  const float* uop    = (const float*)d_in[7];
  const float* iop    = (const float*)d_in[8];
  const float* Wq = (const float*)d_in[9];  const float* bq = (const float*)d_in[10];
  const float* Wk = (const float*)d_in[11]; const float* bk = (const float*)d_in[12];
  const float* Wv = (const float*)d_in[13]; const float* bv = (const float*)d_in[14];
  const float* Wo = (const float*)d_in[15]; const float* bo = (const float*)d_in[16];
  const float* g1 = (const float*)d_in[17]; const float* b1 = (const float*)d_in[18];
  const float* Wi = (const float*)d_in[19]; const float* bi = (const float*)d_in[20];
  const float* Wf = (const float*)d_in[21]; const float* bf = (const float*)d_in[22];
  const float* g2 = (const float*)d_in[23]; const float* b2 = (const float*)d_in[24];
  const float* Wagg = (const float*)d_in[25]; const float* bagg = (const float*)d_in[26];
  const float* Wd1 = (const float*)d_in[27]; const float* bd1 = (const float*)d_in[28];
  const float* l1g = (const float*)d_in[29]; const float* l1b = (const float*)d_in[30];
  const float* Wd2 = (const float*)d_in[31]; const float* bd2 = (const float*)d_in[32];
  const float* l2g = (const float*)d_in[33]; const float* l2b = (const float*)d_in[34];

  // ---- workspace layout (floats) ----
  const size_t CSEQ = 1024;                 // sequences per chunk
  const size_t CS = CSEQ * SEQ * E;         // 8,388,608 floats per chunk buffer
  float* ws = (float*)d_ws;
  float* qb   = ws;
  float* kb   = qb + CS;
  float* vb   = kb + CS;
  float* h101 = vb + CS;                    // [4096][2][256]
  float* h1n0 = h101 + (size_t)4096 * 2 * E;// [64][32][256]
  float* p1_0 = h1n0 + (size_t)64 * SEQ * E;
  float* p2_0 = p1_0 + 64 * E;
  float* p1_1 = p2_0 + 64 * E;
  float* p2_1 = p1_1 + 64 * E;
  float* agg0 = p2_1 + 64 * E;
  float* agg1 = agg0 + 64 * E;
  float* h2in = agg1 + 64 * E;              // [64][32][256]
  float* q2   = h2in + (size_t)64 * SEQ * E;
  float* k2   = q2 + (size_t)64 * SEQ * E;
  float* v2   = k2 + (size_t)64 * SEQ * E;
  float* a2   = v2 + (size_t)64 * SEQ * E;
  float* h2   = a2 + (size_t)64 * SEQ * E;
  size_t need = (size_t)(h2 + (size_t)64 * SEQ * E - ws) * sizeof(float);
  if (ws_size < need) return;  // insufficient scratch: leave output poisoned (visible failure)

  // ================= iteration 0 =================
  prop_ln_kernel<<<64, 256, 0, stream>>>(qemb, nullptr, 0, uop, Wd1, bd1, l1g, l1b, p1_0, 0);
  prop_ln_kernel<<<64, 256, 0, stream>>>(kemb, nullptr, 1, iop, Wd2, bd2, l2g, l2b, p2_0, 1);

  for (int c = 0; c < 4; ++c) {
    size_t sb = (size_t)c * CSEQ;                 // absolute first sequence of chunk
    const float* Ain = hidden + sb * SEQ * E;
    qkv_kernel<<<(int)CSEQ, 256, 0, stream>>>(Ain, Wq, bq, Wk, bk, Wv, bv, qb, kb, vb);
    attn_kernel<<<dim3((int)CSEQ, 4), 256, 0, stream>>>(qb, kb, vb, qb,
                                                        amask + sb * SEQ, SEQ, 1);
    ln_gemm_kernel<<<(int)CSEQ, 256, 0, stream>>>(qb, Wo, bo, Ain, g1, b1, kb);
    ffn_kernel<<<(int)CSEQ, 256, 0, stream>>>(kb, Wi, bi, Wf, bf, g2, b2,
                                              nullptr, h101, h1n0, (int)sb);
  }
  agg_kernel<<<64, 256, 0, stream>>>(h1n0, SEQ * E, p1_0, p2_0, Wagg, bagg, agg0);

  // ================= iteration 1 (n==0 sequences only) =================
  prop_ln_kernel<<<64, 256, 0, stream>>>(qemb, h101, 0, uop, Wd1, bd1, l1g, l1b, p1_1, 0);
  prop_ln_kernel<<<64, 256, 0, stream>>>(kemb, h101, 1, iop, Wd2, bd2, l2g, l2b, p2_1, 1);
  build_h2_kernel<<<64, 256, 0, stream>>>(qemb, kemb, demb, cemb, agg0, h1n0, h2in);

  const float* Wq1 = Wq + E * E;   const float* bq1 = bq + E;
  const float* Wk1 = Wk + E * E;   const float* bk1 = bk + E;
  const float* Wv1 = Wv + E * E;   const float* bv1 = bv + E;
  const float* Wo1 = Wo + E * E;   const float* bo1 = bo + E;
  const float* g11 = g1 + E;       const float* b11 = b1 + E;
  const float* Wi1 = Wi + E * FF;  const float* bi1 = bi + FF;
  const float* Wf1 = Wf + FF * E;  const float* bf1 = bf + E;
  const float* g21 = g2 + E;       const float* b21 = b2 + E;

  qkv_kernel<<<64, 256, 0, stream>>>(h2in, Wq1, bq1, Wk1, bk1, Wv1, bv1, q2, k2, v2);
  attn_kernel<<<dim3(64, 4), 256, 0, stream>>>(q2, k2, v2, q2, amask, 64 * SEQ, 0);
  ln_gemm_kernel<<<64, 256, 0, stream>>>(q2, Wo1, bo1, h2in, g11, b11, a2);
  ffn_kernel<<<64, 256, 0, stream>>>(a2, Wi1, bi1, Wf1, bf1, g21, b21,
                                     h2, nullptr, nullptr, 0);
  agg_kernel<<<64, 256, 0, stream>>>(h2, SEQ * E, p1_1, p2_1,
                                     Wagg + (size_t)768 * E, bagg + E, agg1);

  out_kernel<<<64, 256, 0, stream>>>(h1n0, agg0, h2, agg1, (float*)d_out);
}

// Round 2
// 2287.621 us; speedup vs baseline: 2.5833x; 2.5833x over previous
//
#include <hip/hip_runtime.h>
#include <math.h>

#define E 256
#define SEQ 32
#define FF 1024
#define NEG_MASK -10000.0f

// ---------- helpers ----------
__device__ __forceinline__ float block_sum256(float v, float* tmp4) {
  #pragma unroll
  for (int o = 32; o > 0; o >>= 1) v += __shfl_down(v, o);
  int wid = threadIdx.x >> 6, lane = threadIdx.x & 63;
  if (lane == 0) tmp4[wid] = v;
  __syncthreads();
  float r = tmp4[0] + tmp4[1] + tmp4[2] + tmp4[3];
  __syncthreads();
  return r;
}

// ---------- sparse prop + W_d + LN (one row of output per batch) ----------
__global__ __launch_bounds__(256) void prop_ln_kernel(
    const float* __restrict__ emb, const float* snq, int snq_off,
    const float* __restrict__ op, const float* __restrict__ Wd,
    const float* __restrict__ bd, const float* __restrict__ g,
    const float* __restrict__ bvec, float* __restrict__ outp, int row) {
  __shared__ float wv[64];
  __shared__ int gi[64];
  __shared__ float s1[16 * E];
  __shared__ float s2[16 * E];
  __shared__ float t2row[E];
  __shared__ float tmp4[4];
  int b = blockIdx.x, e = threadIdx.x;
  if (e < 64) {
    wv[e] = op[(b * 64 + e) * 2 + 1];
    gi[e] = (int)op[(b * 64 + e) * 2 + 0];
  }
  for (int gg = 0; gg < 16; ++gg) { s1[gg * E + e] = 0.f; s2[gg * E + e] = 0.f; }
  __syncthreads();
  float t0r = 0.f;
  for (int n = 0; n < 64; ++n) {
    float t0 = 0.5f * emb[(b * 64 + n) * E + e];
    if (snq) t0 += snq[((size_t)(b * 64 + n) * 2 + snq_off) * E + e];
    if (n == row) t0r = t0;
    s1[gi[n] * E + e] += wv[n] * t0;  // column-private: no races
  }
  for (int n = 0; n < 64; ++n) {
    float t0 = 0.5f * emb[(b * 64 + n) * E + e];
    if (snq) t0 += snq[((size_t)(b * 64 + n) * 2 + snq_off) * E + e];
    float t1 = wv[n] * s1[gi[n] * E + e] + 0.1f * t0;
    s2[gi[n] * E + e] += wv[n] * t1;
  }
  float t2 = wv[row] * s2[gi[row] * E + e] + 0.1f * t0r;
  t2row[e] = t2;
  __syncthreads();
  float y = bd[e];
  for (int k = 0; k < E; ++k) y = fmaf(t2row[k], Wd[k * E + e], y);
  float ssum = block_sum256(y, tmp4);
  float qsum = block_sum256(y * y, tmp4);
  float m = ssum * (1.f / E);
  float var = qsum * (1.f / E) - m * m;
  outp[b * E + e] = (y - m) * rsqrtf(var + 1e-12f) * g[e] + bvec[e];
}

// ---------- fused per-sequence: K,V,Q(rows 0,1) projection + attention ----------
// One block per sequence. Only ctx rows 0,1 are produced (compact).
__global__ __launch_bounds__(256) void seq_attn_kernel(
    const float* __restrict__ A,
    const float* __restrict__ Wq, const float* __restrict__ bq,
    const float* __restrict__ Wk, const float* __restrict__ bk,
    const float* __restrict__ Wv, const float* __restrict__ bv,
    const float* __restrict__ mask, int set4, float* __restrict__ ctx2) {
  __shared__ float aT[32][E];
  __shared__ float kv[32][257];   // stride 257 words -> conflict-free column reads
  __shared__ float qs[2][E];
  __shared__ float pr[4][2][33];
  int a = blockIdx.x, t = threadIdx.x;
  size_t abase = (size_t)a * (SEQ * E);
  for (int r = 0; r < 32; ++r) aT[r][t] = A[abase + r * E + t];
  __syncthreads();
  // ---- K (all rows) + Q (rows 0,1) projection ----
  {
    float acck[32];
    float bkv = bk[t];
    #pragma unroll
    for (int r = 0; r < 32; ++r) acck[r] = bkv;
    float q0 = bq[t], q1 = bq[t];
    for (int e0 = 0; e0 < E; e0 += 4) {
      float wk0 = Wk[(e0+0)*E+t], wk1 = Wk[(e0+1)*E+t], wk2 = Wk[(e0+2)*E+t], wk3 = Wk[(e0+3)*E+t];
      float wq0 = Wq[(e0+0)*E+t], wq1 = Wq[(e0+1)*E+t], wq2 = Wq[(e0+2)*E+t], wq3 = Wq[(e0+3)*E+t];
      #pragma unroll
      for (int r = 0; r < 32; ++r) {
        float4 a4 = *(const float4*)&aT[r][e0];
        acck[r] = fmaf(a4.x, wk0, fmaf(a4.y, wk1, fmaf(a4.z, wk2, fmaf(a4.w, wk3, acck[r]))));
        if (r == 0) q0 = fmaf(a4.x, wq0, fmaf(a4.y, wq1, fmaf(a4.z, wq2, fmaf(a4.w, wq3, q0))));
        if (r == 1) q1 = fmaf(a4.x, wq0, fmaf(a4.y, wq1, fmaf(a4.z, wq2, fmaf(a4.w, wq3, q1))));
      }
    }
    #pragma unroll
    for (int r = 0; r < 32; ++r) kv[r][t] = acck[r];
    qs[0][t] = q0; qs[1][t] = q1;
  }
  __syncthreads();
  // ---- scores + softmax (thread t -> head h=t>>6, qrow=(t>>5)&1, key tt=t&31) ----
  {
    int h = t >> 6, qr = (t >> 5) & 1, tt = t & 31;
    float acc = 0.f;
    #pragma unroll
    for (int d = 0; d < 64; ++d) acc = fmaf(qs[qr][h * 64 + d], kv[tt][h * 64 + d], acc);
    float mv = mask[(size_t)a * SEQ + tt];
    if (set4 && tt < 4) mv = NEG_MASK;
    float sc = acc * 0.125f + mv;
    float mx = sc;
    mx = fmaxf(mx, __shfl_xor(mx, 1));
    mx = fmaxf(mx, __shfl_xor(mx, 2));
    mx = fmaxf(mx, __shfl_xor(mx, 4));
    mx = fmaxf(mx, __shfl_xor(mx, 8));
    mx = fmaxf(mx, __shfl_xor(mx, 16));
    float ex = expf(sc - mx);
    float se = ex;
    se += __shfl_xor(se, 1); se += __shfl_xor(se, 2); se += __shfl_xor(se, 4);
    se += __shfl_xor(se, 8); se += __shfl_xor(se, 16);
    pr[h][qr][tt] = ex / se;
  }
  __syncthreads();   // all K reads done; kv may be overwritten with V
  // ---- V projection (overwrites kv) ----
  {
    float accv[32];
    float bvv = bv[t];
    #pragma unroll
    for (int r = 0; r < 32; ++r) accv[r] = bvv;
    for (int e0 = 0; e0 < E; e0 += 4) {
      float w0 = Wv[(e0+0)*E+t], w1 = Wv[(e0+1)*E+t], w2 = Wv[(e0+2)*E+t], w3 = Wv[(e0+3)*E+t];
      #pragma unroll
      for (int r = 0; r < 32; ++r) {
        float4 a4 = *(const float4*)&aT[r][e0];
        accv[r] = fmaf(a4.x, w0, fmaf(a4.y, w1, fmaf(a4.z, w2, fmaf(a4.w, w3, accv[r]))));
      }
    }
    #pragma unroll
    for (int r = 0; r < 32; ++r) kv[r][t] = accv[r];
  }
  __syncthreads();
  // ---- PV: ctx rows 0,1 ----
  {
    int h = t >> 6;
    #pragma unroll
    for (int qr = 0; qr < 2; ++qr) {
      float acc = 0.f;
      #pragma unroll
      for (int tt = 0; tt < 32; ++tt) acc = fmaf(pr[h][qr][tt], kv[tt][t], acc);
      ctx2[((size_t)a * 2 + qr) * E + t] = acc;
    }
  }
}

// ---------- full Q/K/V projection (strided seq input, compact output) ----------
__global__ __launch_bounds__(256) void qkv_kernel(
    const float* __restrict__ A, int seq_stride,
    const float* __restrict__ Wq, const float* __restrict__ bq,
    const float* __restrict__ Wk, const float* __restrict__ bk,
    const float* __restrict__ Wv, const float* __restrict__ bv,
    float* __restrict__ Q, float* __restrict__ K, float* __restrict__ V) {
  __shared__ float aT[32][E];
  int t = threadIdx.x;
  size_t inb = (size_t)blockIdx.x * seq_stride * SEQ;
  int row0 = blockIdx.x * 32;
  for (int r = 0; r < 32; ++r) aT[r][t] = A[(inb + r) * E + t];
  __syncthreads();
  float accq[32], acck[32], accv[32];
  float bqv = bq[t], bkv = bk[t], bvv = bv[t];
  #pragma unroll
  for (int r = 0; r < 32; ++r) { accq[r] = bqv; acck[r] = bkv; accv[r] = bvv; }
  for (int e0 = 0; e0 < E; e0 += 4) {
    float wq0 = Wq[(e0+0)*E+t], wq1 = Wq[(e0+1)*E+t], wq2 = Wq[(e0+2)*E+t], wq3 = Wq[(e0+3)*E+t];
    float wk0 = Wk[(e0+0)*E+t], wk1 = Wk[(e0+1)*E+t], wk2 = Wk[(e0+2)*E+t], wk3 = Wk[(e0+3)*E+t];
    float wv0 = Wv[(e0+0)*E+t], wv1 = Wv[(e0+1)*E+t], wv2 = Wv[(e0+2)*E+t], wv3 = Wv[(e0+3)*E+t];
    #pragma unroll
    for (int r = 0; r < 32; ++r) {
      float4 a4 = *(const float4*)&aT[r][e0];
      accq[r] = fmaf(a4.x, wq0, fmaf(a4.y, wq1, fmaf(a4.z, wq2, fmaf(a4.w, wq3, accq[r]))));
      acck[r] = fmaf(a4.x, wk0, fmaf(a4.y, wk1, fmaf(a4.z, wk2, fmaf(a4.w, wk3, acck[r]))));
      accv[r] = fmaf(a4.x, wv0, fmaf(a4.y, wv1, fmaf(a4.z, wv2, fmaf(a4.w, wv3, accv[r]))));
    }
  }
  for (int r = 0; r < 32; ++r) {
    size_t o = (size_t)(row0 + r) * E + t;
    Q[o] = accq[r]; K[o] = acck[r]; V[o] = accv[r];
  }
}

// ---------- full attention: one block per (sequence, head). CTX may alias Q. ----------
__global__ __launch_bounds__(256) void attn_kernel(
    const float* Q, const float* K, const float* V, float* CTX,
    const float* __restrict__ mask, int mask_stride, int set4) {
  int a = blockIdx.x, h = blockIdx.y, t = threadIdx.x;
  __shared__ float qs[32][65], ks[32][65], vs[32][65];
  __shared__ float pr[32][33];
  size_t base = (size_t)a * (SEQ * E) + h * 64;
  for (int i = 0; i < 8; ++i) {
    int p = i * 256 + t; int s = p >> 6, d = p & 63;
    qs[s][d] = Q[base + s * E + d];
    ks[s][d] = K[base + s * E + d];
    vs[s][d] = V[base + s * E + d];
  }
  __syncthreads();
  for (int i = 0; i < 4; ++i) {
    int p = i * 256 + t; int s = p >> 5, tt = p & 31;
    float acc = 0.f;
    #pragma unroll
    for (int d = 0; d < 64; ++d) acc = fmaf(qs[s][d], ks[tt][d], acc);
    float mv = mask[(size_t)a * mask_stride + tt];
    if (set4 && tt < 4) mv = NEG_MASK;
    pr[s][tt] = acc * 0.125f + mv;
  }
  __syncthreads();
  int rrow = t >> 3, l = t & 7;
  float vals[4];
  float mx = -1e30f;
  #pragma unroll
  for (int ii = 0; ii < 4; ++ii) { vals[ii] = pr[rrow][l + ii * 8]; mx = fmaxf(mx, vals[ii]); }
  mx = fmaxf(mx, __shfl_xor(mx, 1));
  mx = fmaxf(mx, __shfl_xor(mx, 2));
  mx = fmaxf(mx, __shfl_xor(mx, 4));
  float se = 0.f;
  #pragma unroll
  for (int ii = 0; ii < 4; ++ii) { vals[ii] = expf(vals[ii] - mx); se += vals[ii]; }
  se += __shfl_xor(se, 1); se += __shfl_xor(se, 2); se += __shfl_xor(se, 4);
  float inv = 1.f / se;
  #pragma unroll
  for (int ii = 0; ii < 4; ++ii) pr[rrow][l + ii * 8] = vals[ii] * inv;
  __syncthreads();
  for (int i = 0; i < 8; ++i) {
    int p = i * 256 + t; int s = p >> 6, d = p & 63;
    float acc = 0.f;
    #pragma unroll
    for (int tt = 0; tt < SEQ; ++tt) acc = fmaf(pr[s][tt], vs[tt][d], acc);
    CTX[base + s * E + d] = acc;
  }
}

// ---------- GEMM(K=256) + bias + residual(strided) + LayerNorm (compact A/OUT) ----------
__global__ __launch_bounds__(256) void ln_gemm_kernel(
    const float* __restrict__ A, const float* __restrict__ W,
    const float* __restrict__ bias, const float* __restrict__ Res, int seq_stride,
    const float* __restrict__ g, const float* __restrict__ bvec,
    float* __restrict__ OUT) {
  __shared__ float aT[32][E];
  __shared__ float prs[32][4], prq[32][4];
  int row0 = blockIdx.x * 32, t = threadIdx.x;
  size_t resb = (size_t)blockIdx.x * seq_stride * SEQ;
  for (int r = 0; r < 32; ++r) aT[r][t] = A[(size_t)(row0 + r) * E + t];
  __syncthreads();
  float acc[32];
  float bv = bias[t];
  #pragma unroll
  for (int r = 0; r < 32; ++r) acc[r] = bv;
  for (int e0 = 0; e0 < E; e0 += 4) {
    float w0 = W[(e0+0)*E+t], w1 = W[(e0+1)*E+t], w2 = W[(e0+2)*E+t], w3 = W[(e0+3)*E+t];
    #pragma unroll
    for (int r = 0; r < 32; ++r) {
      float4 a4 = *(const float4*)&aT[r][e0];
      acc[r] = fmaf(a4.x, w0, fmaf(a4.y, w1, fmaf(a4.z, w2, fmaf(a4.w, w3, acc[r]))));
    }
  }
  #pragma unroll
  for (int r = 0; r < 32; ++r) acc[r] += Res[(resb + r) * E + t];
  int wid = t >> 6, lane = t & 63;
  for (int r = 0; r < 32; ++r) {
    float s = acc[r], q = acc[r] * acc[r];
    #pragma unroll
    for (int o = 32; o > 0; o >>= 1) { s += __shfl_down(s, o); q += __shfl_down(q, o); }
    if (lane == 0) { prs[r][wid] = s; prq[r][wid] = q; }
  }
  __syncthreads();
  #pragma unroll
  for (int r = 0; r < 32; ++r) {
    float Sv = prs[r][0] + prs[r][1] + prs[r][2] + prs[r][3];
    float Qv = prq[r][0] + prq[r][1] + prq[r][2] + prq[r][3];
    float m = Sv * (1.f / E), var = Qv * (1.f / E) - m * m;
    OUT[(size_t)(row0 + r) * E + t] = (acc[r] - m) * rsqrtf(var + 1e-12f) * g[t] + bvec[t];
  }
}

// ---------- compact-row Wo+LN: rows are (seq, r01) pairs; residual from hidden ----------
__global__ __launch_bounds__(256) void ln_gemm2_kernel(
    const float* __restrict__ A, const float* __restrict__ W,
    const float* __restrict__ bias, const float* __restrict__ hidden,
    const float* __restrict__ g, const float* __restrict__ bvec,
    float* __restrict__ OUT) {
  __shared__ float aT[32][E];
  __shared__ float prs[32][4], prq[32][4];
  int row0 = blockIdx.x * 32, t = threadIdx.x;
  for (int r = 0; r < 32; ++r) aT[r][t] = A[(size_t)(row0 + r) * E + t];
  __syncthreads();
  float acc[32];
  float bv = bias[t];
  #pragma unroll
  for (int r = 0; r < 32; ++r) acc[r] = bv;
  for (int e0 = 0; e0 < E; e0 += 4) {
    float w0 = W[(e0+0)*E+t], w1 = W[(e0+1)*E+t], w2 = W[(e0+2)*E+t], w3 = W[(e0+3)*E+t];
    #pragma unroll
    for (int r = 0; r < 32; ++r) {
      float4 a4 = *(const float4*)&aT[r][e0];
      acc[r] = fmaf(a4.x, w0, fmaf(a4.y, w1, fmaf(a4.z, w2, fmaf(a4.w, w3, acc[r]))));
    }
  }
  #pragma unroll
  for (int r = 0; r < 32; ++r) {
    int R = row0 + r;
    acc[r] += hidden[((size_t)(R >> 1) * SEQ + (R & 1)) * E + t];
  }
  int wid = t >> 6, lane = t & 63;
  for (int r = 0; r < 32; ++r) {
    float s = acc[r], q = acc[r] * acc[r];
    #pragma unroll
    for (int o = 32; o > 0; o >>= 1) { s += __shfl_down(s, o); q += __shfl_down(q, o); }
    if (lane == 0) { prs[r][wid] = s; prq[r][wid] = q; }
  }
  __syncthreads();
  #pragma unroll
  for (int r = 0; r < 32; ++r) {
    float Sv = prs[r][0] + prs[r][1] + prs[r][2] + prs[r][3];
    float Qv = prq[r][0] + prq[r][1] + prq[r][2] + prq[r][3];
    float m = Sv * (1.f / E), var = Qv * (1.f / E) - m * m;
    OUT[(size_t)(row0 + r) * E + t] = (acc[r] - m) * rsqrtf(var + 1e-12f) * g[t] + bvec[t];
  }
}

// ---------- fused FFN (16 rows/block): LN(gelu(A@Wi+bi)@Wf + bf + A) ----------
__global__ __launch_bounds__(256) void ffn16_kernel(
    const float* __restrict__ A,
    const float* __restrict__ Wi, const float* __restrict__ bi,
    const float* __restrict__ Wf, const float* __restrict__ bf,
    const float* __restrict__ g, const float* __restrict__ bvec,
    float* __restrict__ out) {
  __shared__ float aT[16][E];
  __shared__ float fT[16][E];
  __shared__ float prs[16][4], prq[16][4];
  int row0 = blockIdx.x * 16, t = threadIdx.x;
  for (int r = 0; r < 16; ++r) aT[r][t] = A[(size_t)(row0 + r) * E + t];
  __syncthreads();
  float acch[16];
  float bfv = bf[t];
  #pragma unroll
  for (int r = 0; r < 16; ++r) acch[r] = bfv + aT[r][t];  // bias + residual
  for (int c = 0; c < 4; ++c) {
    int j = c * 256 + t;
    float accf[16];
    float biv = bi[j];
    #pragma unroll
    for (int r = 0; r < 16; ++r) accf[r] = biv;
    for (int e0 = 0; e0 < E; e0 += 4) {
      float w0 = Wi[(e0+0)*FF+j], w1 = Wi[(e0+1)*FF+j], w2 = Wi[(e0+2)*FF+j], w3 = Wi[(e0+3)*FF+j];
      #pragma unroll
      for (int r = 0; r < 16; ++r) {
        float4 a4 = *(const float4*)&aT[r][e0];
        accf[r] = fmaf(a4.x, w0, fmaf(a4.y, w1, fmaf(a4.z, w2, fmaf(a4.w, w3, accf[r]))));
      }
    }
    if (c > 0) __syncthreads();
    #pragma unroll
    for (int r = 0; r < 16; ++r) {
      float x = accf[r];
      fT[r][t] = 0.5f * x * (1.f + erff(x * 0.70710678118654752f));
    }
    __syncthreads();
    for (int j0 = 0; j0 < 256; j0 += 4) {
      float w0 = Wf[(c*256+j0+0)*E+t], w1 = Wf[(c*256+j0+1)*E+t],
            w2 = Wf[(c*256+j0+2)*E+t], w3 = Wf[(c*256+j0+3)*E+t];
      #pragma unroll
      for (int r = 0; r < 16; ++r) {
        float4 f4 = *(const float4*)&fT[r][j0];
        acch[r] = fmaf(f4.x, w0, fmaf(f4.y, w1, fmaf(f4.z, w2, fmaf(f4.w, w3, acch[r]))));
      }
    }
  }
  int wid = t >> 6, lane = t & 63;
  for (int r = 0; r < 16; ++r) {
    float s = acch[r], q = acch[r] * acch[r];
    #pragma unroll
    for (int o = 32; o > 0; o >>= 1) { s += __shfl_down(s, o); q += __shfl_down(q, o); }
    if (lane == 0) { prs[r][wid] = s; prq[r][wid] = q; }
  }
  __syncthreads();
  #pragma unroll
  for (int r = 0; r < 16; ++r) {
    float Sv = prs[r][0] + prs[r][1] + prs[r][2] + prs[r][3];
    float Qv = prq[r][0] + prq[r][1] + prq[r][2] + prq[r][3];
    float m = Sv * (1.f / E), var = Qv * (1.f / E) - m * m;
    out[(size_t)(row0 + r) * E + t] = (acch[r] - m) * rsqrtf(var + 1e-12f) * g[t] + bvec[t];
  }
}

// ---------- agg: l2norm(relu([l2norm(hrow4), p1, p2] @ Wagg + bagg)) ----------
__global__ __launch_bounds__(256) void agg_kernel(
    const float* __restrict__ hbase, int hstride,
    const float* __restrict__ p1, const float* __restrict__ p2,
    const float* __restrict__ Wagg, const float* __restrict__ bagg,
    float* __restrict__ outp) {
  __shared__ float pv[768];
  __shared__ float tmp4[4];
  int b = blockIdx.x, t = threadIdx.x;
  float x = hbase[(size_t)b * hstride + 4 * E + t];
  float n2 = block_sum256(x * x, tmp4);
  pv[t] = x / fmaxf(sqrtf(n2), 1e-12f);
  pv[256 + t] = p1[b * E + t];
  pv[512 + t] = p2[b * E + t];
  __syncthreads();
  float y = bagg[t];
  for (int u = 0; u < 768; ++u) y = fmaf(pv[u], Wagg[u * E + t], y);
  y = fmaxf(y, 0.f);
  float n3 = block_sum256(y * y, tmp4);
  outp[b * E + t] = y / fmaxf(sqrtf(n3), 1e-12f);
}

// ---------- build iter-1 input for n==0 sequences ----------
__global__ __launch_bounds__(256) void build_h2_kernel(
    const float* __restrict__ qe, const float* __restrict__ ke,
    const float* __restrict__ de, const float* __restrict__ ce,
    const float* __restrict__ agg0, const float* __restrict__ h1n0,
    float* __restrict__ h2in) {
  int b = blockIdx.x, t = threadIdx.x;
  size_t eb = (size_t)(b * 64) * E + t;  // embedding at (b, n=0)
  size_t ob = (size_t)b * (SEQ * E);
  h2in[ob + 0 * E + t] = qe[eb];
  h2in[ob + 1 * E + t] = ke[eb];
  h2in[ob + 2 * E + t] = de[eb];
  h2in[ob + 3 * E + t] = ce[eb];
  h2in[ob + 4 * E + t] = agg0[b * E + t];
  for (int s = 5; s < SEQ; ++s) h2in[ob + s * E + t] = h1n0[ob + s * E + t];
}

// ---------- final output ----------
__global__ __launch_bounds__(256) void out_kernel(
    const float* __restrict__ h1n0, const float* __restrict__ agg0,
    const float* __restrict__ h2, const float* __restrict__ agg1,
    float* __restrict__ outp) {
  int b = blockIdx.x, t = threadIdx.x;
  size_t ob = (size_t)b * (SEQ * E);
  float s1v = agg0[b * E + t];
  float s2v = agg1[b * E + t];
  for (int s = 5; s < SEQ; ++s) { s1v += h1n0[ob + s * E + t]; s2v += h2[ob + s * E + t]; }
  outp[b * E + t] = 0.5f * (s1v + s2v) * (1.f / 28.f);
}

extern "C" void kernel_launch(void* const* d_in, const int* in_sizes, int n_in,
                              void* d_out, int out_size, void* d_ws, size_t ws_size,
                              hipStream_t stream) {
  (void)in_sizes; (void)n_in; (void)out_size;
  const float* hidden = (const float*)d_in[1];
  const float* amask  = (const float*)d_in[2];
  const float* qemb   = (const float*)d_in[3];
  const float* kemb   = (const float*)d_in[4];
  const float* demb   = (const float*)d_in[5];
  const float* cemb   = (const float*)d_in[6];
  const float* uop    = (const float*)d_in[7];
  const float* iop    = (const float*)d_in[8];
  const float* Wq = (const float*)d_in[9];  const float* bq = (const float*)d_in[10];
  const float* Wk = (const float*)d_in[11]; const float* bk = (const float*)d_in[12];
  const float* Wv = (const float*)d_in[13]; const float* bv = (const float*)d_in[14];
  const float* Wo = (const float*)d_in[15]; const float* bo = (const float*)d_in[16];
  const float* g1 = (const float*)d_in[17]; const float* b1 = (const float*)d_in[18];
  const float* Wi = (const float*)d_in[19]; const float* bi = (const float*)d_in[20];
  const float* Wf = (const float*)d_in[21]; const float* bf = (const float*)d_in[22];
  const float* g2 = (const float*)d_in[23]; const float* b2 = (const float*)d_in[24];
  const float* Wagg = (const float*)d_in[25]; const float* bagg = (const float*)d_in[26];
  const float* Wd1 = (const float*)d_in[27]; const float* bd1 = (const float*)d_in[28];
  const float* l1g = (const float*)d_in[29]; const float* l1b = (const float*)d_in[30];
  const float* Wd2 = (const float*)d_in[31]; const float* bd2 = (const float*)d_in[32];
  const float* l2g = (const float*)d_in[33]; const float* l2b = (const float*)d_in[34];

  // ---- workspace layout (floats) ----
  const size_t BIG = (size_t)4096 * 2 * E;   // 2,097,152
  const size_t SML = (size_t)64 * SEQ * E;   // 524,288
  float* ws = (float*)d_ws;
  float* ctx2 = ws;
  float* a01  = ctx2 + BIG;
  float* h101 = a01 + BIG;
  float* q0   = h101 + BIG;     // also ctx0
  float* k0   = q0 + SML;
  float* v0   = k0 + SML;
  float* a0   = v0 + SML;
  float* h1n0 = a0 + SML;
  float* h2in = h1n0 + SML;
  float* q2i  = h2in + SML;
  float* k2i  = q2i + SML;
  float* v2i  = k2i + SML;
  float* a2   = v2i + SML;
  float* h2   = a2 + SML;
  float* p1_0 = h2 + SML;
  float* p2_0 = p1_0 + 64 * E;
  float* p1_1 = p2_0 + 64 * E;
  float* p2_1 = p1_1 + 64 * E;
  float* agg0 = p2_1 + 64 * E;
  float* agg1 = agg0 + 64 * E;
  size_t need = (size_t)(agg1 + 64 * E - ws) * sizeof(float);
  if (ws_size < need) return;

  // ================= iteration 0 =================
  prop_ln_kernel<<<64, 256, 0, stream>>>(qemb, nullptr, 0, uop, Wd1, bd1, l1g, l1b, p1_0, 0);
  prop_ln_kernel<<<64, 256, 0, stream>>>(kemb, nullptr, 1, iop, Wd2, bd2, l2g, l2b, p2_0, 1);

  // compact path: rows 0,1 of ALL 4096 sequences
  seq_attn_kernel<<<4096, 256, 0, stream>>>(hidden, Wq, bq, Wk, bk, Wv, bv, amask, 1, ctx2);
  ln_gemm2_kernel<<<256, 256, 0, stream>>>(ctx2, Wo, bo, hidden, g1, b1, a01);
  ffn16_kernel<<<512, 256, 0, stream>>>(a01, Wi, bi, Wf, bf, g2, b2, h101);

  // n==0 path: full 64 sequences (seq stride 64 in `hidden`)
  qkv_kernel<<<64, 256, 0, stream>>>(hidden, 64, Wq, bq, Wk, bk, Wv, bv, q0, k0, v0);
  attn_kernel<<<dim3(64, 4), 256, 0, stream>>>(q0, k0, v0, q0, amask, 64 * SEQ, 1);
  ln_gemm_kernel<<<64, 256, 0, stream>>>(q0, Wo, bo, hidden, 64, g1, b1, a0);
  ffn16_kernel<<<128, 256, 0, stream>>>(a0, Wi, bi, Wf, bf, g2, b2, h1n0);

  agg_kernel<<<64, 256, 0, stream>>>(h1n0, SEQ * E, p1_0, p2_0, Wagg, bagg, agg0);

  // ================= iteration 1 (n==0 sequences only) =================
  prop_ln_kernel<<<64, 256, 0, stream>>>(qemb, h101, 0, uop, Wd1, bd1, l1g, l1b, p1_1, 0);
  prop_ln_kernel<<<64, 256, 0, stream>>>(kemb, h101, 1, iop, Wd2, bd2, l2g, l2b, p2_1, 1);
  build_h2_kernel<<<64, 256, 0, stream>>>(qemb, kemb, demb, cemb, agg0, h1n0, h2in);

  const float* Wq1 = Wq + E * E;   const float* bq1 = bq + E;
  const float* Wk1 = Wk + E * E;   const float* bk1 = bk + E;
  const float* Wv1 = Wv + E * E;   const float* bv1 = bv + E;
  const float* Wo1 = Wo + E * E;   const float* bo1 = bo + E;
  const float* g11 = g1 + E;       const float* b11 = b1 + E;
  const float* Wi1 = Wi + E * FF;  const float* bi1 = bi + FF;
  const float* Wf1 = Wf + FF * E;  const float* bf1 = bf + E;
  const float* g21 = g2 + E;       const float* b21 = b2 + E;

  qkv_kernel<<<64, 256, 0, stream>>>(h2in, 1, Wq1, bq1, Wk1, bk1, Wv1, bv1, q2i, k2i, v2i);
  attn_kernel<<<dim3(64, 4), 256, 0, stream>>>(q2i, k2i, v2i, q2i, amask, 64 * SEQ, 0);
  ln_gemm_kernel<<<64, 256, 0, stream>>>(q2i, Wo1, bo1, h2in, 1, g11, b11, a2);
  ffn16_kernel<<<128, 256, 0, stream>>>(a2, Wi1, bi1, Wf1, bf1, g21, b21, h2);
  agg_kernel<<<64, 256, 0, stream>>>(h2, SEQ * E, p1_1, p2_1,
                                     Wagg + (size_t)768 * E, bagg + E, agg1);

  out_kernel<<<64, 256, 0, stream>>>(h1n0, agg0, h2, agg1, (float*)d_out);
}

// Round 3
// 773.156 us; speedup vs baseline: 7.6434x; 2.9588x over previous
//
#include <hip/hip_runtime.h>
#include <math.h>

#define E 256
#define SEQ 32
#define FF 1024
#define NEG_MASK -10000.0f

typedef __attribute__((ext_vector_type(8))) short bf16x8;
typedef __attribute__((ext_vector_type(4))) float f32x4;

__device__ __forceinline__ float bf2f(unsigned short u) {
  unsigned v = ((unsigned)u) << 16; float f; __builtin_memcpy(&f, &v, 4); return f;
}
__device__ __forceinline__ unsigned short f2bf(float f) {
  unsigned u; __builtin_memcpy(&u, &f, 4);
  unsigned r = (u + 0x7fffu + ((u >> 16) & 1u)) >> 16;
  return (unsigned short)r;
}
__device__ __forceinline__ f32x4 mfma16(bf16x8 a, bf16x8 b, f32x4 c) {
  return __builtin_amdgcn_mfma_f32_16x16x32_bf16(a, b, c, 0, 0, 0);
}
__device__ __forceinline__ float block_sum256(float v, float* tmp4) {
  #pragma unroll
  for (int o = 32; o > 0; o >>= 1) v += __shfl_down(v, o);
  int wid = threadIdx.x >> 6, lane = threadIdx.x & 63;
  if (lane == 0) tmp4[wid] = v;
  __syncthreads();
  float r = tmp4[0] + tmp4[1] + tmp4[2] + tmp4[3];
  __syncthreads();
  return r;
}

// ---------------- weight prep: fp32 W[k][n] -> bf16 Wt[n][k], per layer ----------------
__global__ __launch_bounds__(256) void wprep_kernel(
    const float* __restrict__ Wq, const float* __restrict__ Wk,
    const float* __restrict__ Wv, const float* __restrict__ Wo,
    const float* __restrict__ Wi, const float* __restrict__ Wf,
    unsigned short* wqt, unsigned short* wkt, unsigned short* wvt,
    unsigned short* wot, unsigned short* wit, unsigned short* wft) {
  int type = blockIdx.y, l = blockIdx.z, t = threadIdx.x;
  const float* src; unsigned short* dst; int Kd, Nd;
  switch (type) {
    case 0: src = Wq + (size_t)l * 65536; dst = wqt + (size_t)l * 65536; Kd = 256; Nd = 256; break;
    case 1: src = Wk + (size_t)l * 65536; dst = wkt + (size_t)l * 65536; Kd = 256; Nd = 256; break;
    case 2: src = Wv + (size_t)l * 65536; dst = wvt + (size_t)l * 65536; Kd = 256; Nd = 256; break;
    case 3: src = Wo + (size_t)l * 65536; dst = wot + (size_t)l * 65536; Kd = 256; Nd = 256; break;
    case 4: src = Wi + (size_t)l * 262144; dst = wit + (size_t)l * 262144; Kd = 256; Nd = 1024; break;
    default: src = Wf + (size_t)l * 262144; dst = wft + (size_t)l * 262144; Kd = 1024; Nd = 256; break;
  }
  int ntn = Nd >> 5;
  if (blockIdx.x >= (unsigned)((Kd >> 5) * ntn)) return;
  int k0 = (blockIdx.x / ntn) << 5, n0 = (blockIdx.x % ntn) << 5;
  __shared__ float tile[32][33];
  #pragma unroll
  for (int i = 0; i < 4; ++i) {
    int p = i * 256 + t; int kr = p >> 5, nc = p & 31;
    tile[kr][nc] = src[(size_t)(k0 + kr) * Nd + n0 + nc];
  }
  __syncthreads();
  #pragma unroll
  for (int i = 0; i < 4; ++i) {
    int p = i * 256 + t; int nr = p >> 5, kc = p & 31;
    dst[(size_t)(n0 + nr) * Kd + k0 + kc] = f2bf(tile[kc][nr]);
  }
}

// ---------------- sparse prop + W_d + LN (fp32, small) ----------------
__global__ __launch_bounds__(256) void prop_ln_kernel(
    const float* __restrict__ emb, const float* snq, int snq_off,
    const float* __restrict__ op, const float* __restrict__ Wd,
    const float* __restrict__ bd, const float* __restrict__ g,
    const float* __restrict__ bvec, float* __restrict__ outp, int row) {
  __shared__ float wv[64];
  __shared__ int gi[64];
  __shared__ float s1[16 * E];
  __shared__ float s2[16 * E];
  __shared__ float t2row[E];
  __shared__ float tmp4[4];
  int b = blockIdx.x, e = threadIdx.x;
  if (e < 64) {
    wv[e] = op[(b * 64 + e) * 2 + 1];
    gi[e] = (int)op[(b * 64 + e) * 2 + 0];
  }
  for (int gg = 0; gg < 16; ++gg) { s1[gg * E + e] = 0.f; s2[gg * E + e] = 0.f; }
  __syncthreads();
  float t0r = 0.f;
  for (int n = 0; n < 64; ++n) {
    float t0 = 0.5f * emb[(b * 64 + n) * E + e];
    if (snq) t0 += snq[((size_t)(b * 64 + n) * 2 + snq_off) * E + e];
    if (n == row) t0r = t0;
    s1[gi[n] * E + e] += wv[n] * t0;
  }
  for (int n = 0; n < 64; ++n) {
    float t0 = 0.5f * emb[(b * 64 + n) * E + e];
    if (snq) t0 += snq[((size_t)(b * 64 + n) * 2 + snq_off) * E + e];
    float t1 = wv[n] * s1[gi[n] * E + e] + 0.1f * t0;
    s2[gi[n] * E + e] += wv[n] * t1;
  }
  float t2 = wv[row] * s2[gi[row] * E + e] + 0.1f * t0r;
  t2row[e] = t2;
  __syncthreads();
  float y = bd[e];
  for (int k = 0; k < E; ++k) y = fmaf(t2row[k], Wd[k * E + e], y);
  float ssum = block_sum256(y, tmp4);
  float qsum = block_sum256(y * y, tmp4);
  float m = ssum * (1.f / E);
  float var = qsum * (1.f / E) - m * m;
  outp[b * E + e] = (y - m) * rsqrtf(var + 1e-12f) * g[e] + bvec[e];
}

// ---------------- fused per-seq MFMA K/V/Q(0,1) projection + attention ----------------
__global__ __launch_bounds__(256) void seq_attn_mfma(
    const float* __restrict__ hidden,
    const unsigned short* __restrict__ wqt, const float* __restrict__ bq,
    const unsigned short* __restrict__ wkt, const float* __restrict__ bk,
    const unsigned short* __restrict__ wvt, const float* __restrict__ bv,
    const float* __restrict__ mask, unsigned short* __restrict__ ctx_all,
    unsigned short* __restrict__ Kf, unsigned short* __restrict__ Vf) {
  __shared__ unsigned short aT[32][264];
  __shared__ float kv[32][257];
  __shared__ float qs[2][256];
  __shared__ float pr[4][2][33];
  int a = blockIdx.x, t = threadIdx.x;
  int w = t >> 6, l = t & 63;
  int lm = l & 15, lk = (l >> 4) << 3;
  size_t hb = (size_t)a * (SEQ * E);
  for (int r = 0; r < 32; ++r) aT[r][t] = f2bf(hidden[hb + r * E + t]);
  __syncthreads();
  bool isn0 = ((a & 63) == 0);
  int nb = a >> 6;
  f32x4 zz = {0.f, 0.f, 0.f, 0.f};
  // ---- K projection (MFMA) ----
  {
    f32x4 acc[2][4];
    #pragma unroll
    for (int mt = 0; mt < 2; ++mt) for (int nt = 0; nt < 4; ++nt) acc[mt][nt] = zz;
    for (int kc = 0; kc < 8; ++kc) {
      bf16x8 a0 = *(const bf16x8*)&aT[lm][kc * 32 + lk];
      bf16x8 a1 = *(const bf16x8*)&aT[16 + lm][kc * 32 + lk];
      #pragma unroll
      for (int nt = 0; nt < 4; ++nt) {
        bf16x8 bfr = *(const bf16x8*)&wkt[(size_t)(w * 64 + nt * 16 + lm) * 256 + kc * 32 + lk];
        acc[0][nt] = mfma16(a0, bfr, acc[0][nt]);
        acc[1][nt] = mfma16(a1, bfr, acc[1][nt]);
      }
    }
    #pragma unroll
    for (int nt = 0; nt < 4; ++nt) {
      int col = w * 64 + nt * 16 + lm;
      float bb = bk[col];
      #pragma unroll
      for (int mt = 0; mt < 2; ++mt)
        #pragma unroll
        for (int r = 0; r < 4; ++r) {
          int row = mt * 16 + ((l >> 4) << 2) + r;
          float v = acc[mt][nt][r] + bb;
          kv[row][col] = v;
          if (isn0) Kf[((size_t)nb * 32 + row) * 256 + col] = f2bf(v);
        }
    }
  }
  // ---- Q projection rows 0,1 (MFMA, mt=0 only) ----
  {
    f32x4 acc[4];
    #pragma unroll
    for (int nt = 0; nt < 4; ++nt) acc[nt] = zz;
    for (int kc = 0; kc < 8; ++kc) {
      bf16x8 a0 = *(const bf16x8*)&aT[lm][kc * 32 + lk];
      #pragma unroll
      for (int nt = 0; nt < 4; ++nt) {
        bf16x8 bfr = *(const bf16x8*)&wqt[(size_t)(w * 64 + nt * 16 + lm) * 256 + kc * 32 + lk];
        acc[nt] = mfma16(a0, bfr, acc[nt]);
      }
    }
    if ((l >> 4) == 0) {
      #pragma unroll
      for (int nt = 0; nt < 4; ++nt) {
        int col = w * 64 + nt * 16 + lm;
        float bb = bq[col];
        qs[0][col] = acc[nt][0] + bb;
        qs[1][col] = acc[nt][1] + bb;
      }
    }
  }
  __syncthreads();
  // ---- scores + softmax (fp32) ----
  {
    int h = t >> 6, qr = (t >> 5) & 1, tt = t & 31;
    float accs = 0.f;
    #pragma unroll
    for (int d = 0; d < 64; ++d) accs = fmaf(qs[qr][h * 64 + d], kv[tt][h * 64 + d], accs);
    float mv = mask[(size_t)a * SEQ + tt];
    if (tt < 4) mv = NEG_MASK;   // iteration-0 mask
    float sc = accs * 0.125f + mv;
    float mx = sc;
    mx = fmaxf(mx, __shfl_xor(mx, 1));
    mx = fmaxf(mx, __shfl_xor(mx, 2));
    mx = fmaxf(mx, __shfl_xor(mx, 4));
    mx = fmaxf(mx, __shfl_xor(mx, 8));
    mx = fmaxf(mx, __shfl_xor(mx, 16));
    float ex = expf(sc - mx);
    float se = ex;
    se += __shfl_xor(se, 1); se += __shfl_xor(se, 2); se += __shfl_xor(se, 4);
    se += __shfl_xor(se, 8); se += __shfl_xor(se, 16);
    pr[h][qr][tt] = ex / se;
  }
  __syncthreads();
  // ---- V projection (MFMA, overwrites kv) ----
  {
    f32x4 acc[2][4];
    #pragma unroll
    for (int mt = 0; mt < 2; ++mt) for (int nt = 0; nt < 4; ++nt) acc[mt][nt] = zz;
    for (int kc = 0; kc < 8; ++kc) {
      bf16x8 a0 = *(const bf16x8*)&aT[lm][kc * 32 + lk];
      bf16x8 a1 = *(const bf16x8*)&aT[16 + lm][kc * 32 + lk];
      #pragma unroll
      for (int nt = 0; nt < 4; ++nt) {
        bf16x8 bfr = *(const bf16x8*)&wvt[(size_t)(w * 64 + nt * 16 + lm) * 256 + kc * 32 + lk];
        acc[0][nt] = mfma16(a0, bfr, acc[0][nt]);
        acc[1][nt] = mfma16(a1, bfr, acc[1][nt]);
      }
    }
    #pragma unroll
    for (int nt = 0; nt < 4; ++nt) {
      int col = w * 64 + nt * 16 + lm;
      float bb = bv[col];
      #pragma unroll
      for (int mt = 0; mt < 2; ++mt)
        #pragma unroll
        for (int r = 0; r < 4; ++r) {
          int row = mt * 16 + ((l >> 4) << 2) + r;
          float v = acc[mt][nt][r] + bb;
          kv[row][col] = v;
          if (isn0) Vf[((size_t)nb * 32 + row) * 256 + col] = f2bf(v);
        }
    }
  }
  __syncthreads();
  // ---- PV rows 0,1 ----
  {
    int h = t >> 6;
    #pragma unroll
    for (int qr = 0; qr < 2; ++qr) {
      float acc = 0.f;
      #pragma unroll
      for (int tt = 0; tt < 32; ++tt) acc = fmaf(pr[h][qr][tt], kv[tt][t], acc);
      ctx_all[((size_t)a * 2 + qr) * E + t] = f2bf(acc);
    }
  }
}

// ---------------- generic MFMA GEMM + bias (A fp32 gathered, out bf16); M-tile 32 ----------------
__global__ __launch_bounds__(256) void gemm_bias_kernel(
    const float* __restrict__ Af, const unsigned short* __restrict__ Bt,
    const float* __restrict__ bias, unsigned short* __restrict__ outb) {
  __shared__ unsigned short aT[32][264];
  int t = threadIdx.x, w = t >> 6, l = t & 63;
  int lm = l & 15, lk = (l >> 4) << 3;
  int row0 = blockIdx.x * 32;
  for (int r = 0; r < 32; ++r) {
    int gr = row0 + r;
    int src = ((gr >> 5) << 11) + (gr & 31);   // n0 gather: (gr/32)*2048 + gr%32
    aT[r][t] = f2bf(Af[(size_t)src * E + t]);
  }
  __syncthreads();
  f32x4 zz = {0.f, 0.f, 0.f, 0.f};
  f32x4 acc[2][4];
  #pragma unroll
  for (int mt = 0; mt < 2; ++mt) for (int nt = 0; nt < 4; ++nt) acc[mt][nt] = zz;
  for (int kc = 0; kc < 8; ++kc) {
    bf16x8 a0 = *(const bf16x8*)&aT[lm][kc * 32 + lk];
    bf16x8 a1 = *(const bf16x8*)&aT[16 + lm][kc * 32 + lk];
    #pragma unroll
    for (int nt = 0; nt < 4; ++nt) {
      bf16x8 bfr = *(const bf16x8*)&Bt[(size_t)(w * 64 + nt * 16 + lm) * 256 + kc * 32 + lk];
      acc[0][nt] = mfma16(a0, bfr, acc[0][nt]);
      acc[1][nt] = mfma16(a1, bfr, acc[1][nt]);
    }
  }
  #pragma unroll
  for (int nt = 0; nt < 4; ++nt) {
    int col = w * 64 + nt * 16 + lm;
    float bb = bias[col];
    #pragma unroll
    for (int mt = 0; mt < 2; ++mt)
      #pragma unroll
      for (int r = 0; r < 4; ++r) {
        int row = mt * 16 + ((l >> 4) << 2) + r;
        outb[(size_t)(row0 + row) * E + col] = f2bf(acc[mt][nt][r] + bb);
      }
  }
}

// ---------------- 3-in-1 MFMA QKV (A bf16 contiguous) ----------------
__global__ __launch_bounds__(256) void qkv3_kernel(
    const unsigned short* __restrict__ Ab,
    const unsigned short* bt0, const float* b0, unsigned short* o0,
    const unsigned short* bt1, const float* b1, unsigned short* o1,
    const unsigned short* bt2, const float* b2, unsigned short* o2) {
  __shared__ unsigned short aT[32][264];
  int t = threadIdx.x, w = t >> 6, l = t & 63;
  int lm = l & 15, lk = (l >> 4) << 3;
  int row0 = blockIdx.x * 32;
  for (int r = 0; r < 32; ++r) aT[r][t] = Ab[(size_t)(row0 + r) * E + t];
  __syncthreads();
  const unsigned short* bts[3] = {bt0, bt1, bt2};
  const float* bss[3] = {b0, b1, b2};
  unsigned short* oss[3] = {o0, o1, o2};
  f32x4 zz = {0.f, 0.f, 0.f, 0.f};
  for (int m = 0; m < 3; ++m) {
    f32x4 acc[2][4];
    #pragma unroll
    for (int mt = 0; mt < 2; ++mt) for (int nt = 0; nt < 4; ++nt) acc[mt][nt] = zz;
    for (int kc = 0; kc < 8; ++kc) {
      bf16x8 a0 = *(const bf16x8*)&aT[lm][kc * 32 + lk];
      bf16x8 a1 = *(const bf16x8*)&aT[16 + lm][kc * 32 + lk];
      #pragma unroll
      for (int nt = 0; nt < 4; ++nt) {
        bf16x8 bfr = *(const bf16x8*)&bts[m][(size_t)(w * 64 + nt * 16 + lm) * 256 + kc * 32 + lk];
        acc[0][nt] = mfma16(a0, bfr, acc[0][nt]);
        acc[1][nt] = mfma16(a1, bfr, acc[1][nt]);
      }
    }
    #pragma unroll
    for (int nt = 0; nt < 4; ++nt) {
      int col = w * 64 + nt * 16 + lm;
      float bb = bss[m][col];
      #pragma unroll
      for (int mt = 0; mt < 2; ++mt)
        #pragma unroll
        for (int r = 0; r < 4; ++r) {
          int row = mt * 16 + ((l >> 4) << 2) + r;
          oss[m][(size_t)(row0 + row) * E + col] = f2bf(acc[mt][nt][r] + bb);
        }
    }
  }
}

// ---------------- full attention (bf16 in/out), compact 64-seq buffers ----------------
__global__ __launch_bounds__(256) void attnf_kernel(
    const unsigned short* __restrict__ Q, const unsigned short* __restrict__ K,
    const unsigned short* __restrict__ V, unsigned short* __restrict__ CTX,
    const float* __restrict__ mask, int set4) {
  int b = blockIdx.x, h = blockIdx.y, t = threadIdx.x;
  __shared__ float qsh[32][65], ksh[32][65], vsh[32][65];
  __shared__ float pr[32][33];
  size_t base = (size_t)b * (SEQ * E) + h * 64;
  for (int i = 0; i < 8; ++i) {
    int p = i * 256 + t; int s = p >> 6, d = p & 63;
    qsh[s][d] = bf2f(Q[base + s * E + d]);
    ksh[s][d] = bf2f(K[base + s * E + d]);
    vsh[s][d] = bf2f(V[base + s * E + d]);
  }
  __syncthreads();
  for (int i = 0; i < 4; ++i) {
    int p = i * 256 + t; int s = p >> 5, tt = p & 31;
    float acc = 0.f;
    #pragma unroll
    for (int d = 0; d < 64; ++d) acc = fmaf(qsh[s][d], ksh[tt][d], acc);
    float mv = mask[(size_t)b * 2048 + tt];
    if (set4 && tt < 4) mv = NEG_MASK;
    pr[s][tt] = acc * 0.125f + mv;
  }
  __syncthreads();
  int rrow = t >> 3, l8 = t & 7;
  float vals[4];
  float mx = -1e30f;
  #pragma unroll
  for (int ii = 0; ii < 4; ++ii) { vals[ii] = pr[rrow][l8 + ii * 8]; mx = fmaxf(mx, vals[ii]); }
  mx = fmaxf(mx, __shfl_xor(mx, 1));
  mx = fmaxf(mx, __shfl_xor(mx, 2));
  mx = fmaxf(mx, __shfl_xor(mx, 4));
  float se = 0.f;
  #pragma unroll
  for (int ii = 0; ii < 4; ++ii) { vals[ii] = expf(vals[ii] - mx); se += vals[ii]; }
  se += __shfl_xor(se, 1); se += __shfl_xor(se, 2); se += __shfl_xor(se, 4);
  float inv = 1.f / se;
  #pragma unroll
  for (int ii = 0; ii < 4; ++ii) pr[rrow][l8 + ii * 8] = vals[ii] * inv;
  __syncthreads();
  for (int i = 0; i < 8; ++i) {
    int p = i * 256 + t; int s = p >> 6, d = p & 63;
    float acc = 0.f;
    #pragma unroll
    for (int tt = 0; tt < SEQ; ++tt) acc = fmaf(pr[s][tt], vsh[tt][d], acc);
    CTX[base + s * E + d] = f2bf(acc);
  }
}

__device__ __forceinline__ int map_res(int mode, int gr) {
  if (mode == 0) return gr;
  // mode 3: iter0 combined rows
  if (gr < 8192) return ((gr >> 1) << 5) + (gr & 1);
  int rr = gr - 8192;
  return ((rr >> 5) << 11) + (rr & 31);
}

// ---------------- MFMA GEMM(K=256) + bias + residual + LN -> fp32 + bf16 ----------------
__global__ __launch_bounds__(256) void gemm_ln_mfma(
    const unsigned short* __restrict__ Ab, const unsigned short* __restrict__ Bt,
    const float* __restrict__ bias, const float* __restrict__ Res, int resmode,
    const float* __restrict__ g, const float* __restrict__ bvec,
    float* __restrict__ outf, unsigned short* __restrict__ outb) {
  __shared__ unsigned short aT[32][264];
  __shared__ float sT[32][257];
  __shared__ float prs[32][4], prq[32][4];
  int t = threadIdx.x, w = t >> 6, l = t & 63;
  int lm = l & 15, lk = (l >> 4) << 3;
  int row0 = blockIdx.x * 32;
  for (int r = 0; r < 32; ++r) aT[r][t] = Ab[(size_t)(row0 + r) * E + t];
  __syncthreads();
  f32x4 zz = {0.f, 0.f, 0.f, 0.f};
  f32x4 acc[2][4];
  #pragma unroll
  for (int mt = 0; mt < 2; ++mt) for (int nt = 0; nt < 4; ++nt) acc[mt][nt] = zz;
  for (int kc = 0; kc < 8; ++kc) {
    bf16x8 a0 = *(const bf16x8*)&aT[lm][kc * 32 + lk];
    bf16x8 a1 = *(const bf16x8*)&aT[16 + lm][kc * 32 + lk];
    #pragma unroll
    for (int nt = 0; nt < 4; ++nt) {
      bf16x8 bfr = *(const bf16x8*)&Bt[(size_t)(w * 64 + nt * 16 + lm) * 256 + kc * 32 + lk];
      acc[0][nt] = mfma16(a0, bfr, acc[0][nt]);
      acc[1][nt] = mfma16(a1, bfr, acc[1][nt]);
    }
  }
  #pragma unroll
  for (int nt = 0; nt < 4; ++nt) {
    int col = w * 64 + nt * 16 + lm;
    float bb = bias[col];
    #pragma unroll
    for (int mt = 0; mt < 2; ++mt)
      #pragma unroll
      for (int r = 0; r < 4; ++r) {
        int row = mt * 16 + ((l >> 4) << 2) + r;
        int rr = map_res(resmode, row0 + row);
        sT[row][col] = acc[mt][nt][r] + bb + Res[(size_t)rr * E + col];
      }
  }
  __syncthreads();
  // LN: thread t = column
  int wid = t >> 6, lane = t & 63;
  float vcache[32];
  for (int r = 0; r < 32; ++r) {
    float v = sT[r][t];
    vcache[r] = v;
    float s = v, q = v * v;
    #pragma unroll
    for (int o = 32; o > 0; o >>= 1) { s += __shfl_down(s, o); q += __shfl_down(q, o); }
    if (lane == 0) { prs[r][wid] = s; prq[r][wid] = q; }
  }
  __syncthreads();
  #pragma unroll
  for (int r = 0; r < 32; ++r) {
    float Sv = prs[r][0] + prs[r][1] + prs[r][2] + prs[r][3];
    float Qv = prq[r][0] + prq[r][1] + prq[r][2] + prq[r][3];
    float m = Sv * (1.f / E), var = Qv * (1.f / E) - m * m;
    float val = (vcache[r] - m) * rsqrtf(var + 1e-12f) * g[t] + bvec[t];
    outf[(size_t)(row0 + r) * E + t] = val;
    outb[(size_t)(row0 + r) * E + t] = f2bf(val);
  }
}

// ---------------- fused MFMA FFN: LN(gelu(A@Wi+bi)@Wf + bf + Res) ----------------
__global__ __launch_bounds__(256) void ffn_mfma(
    const unsigned short* __restrict__ Ab, const float* __restrict__ Res,
    const unsigned short* __restrict__ WiT, const float* __restrict__ bi,
    const unsigned short* __restrict__ WfT, const float* __restrict__ bfv,
    const float* __restrict__ g, const float* __restrict__ bvec,
    float* __restrict__ out0, float* __restrict__ out1, int split) {
  __shared__ __align__(16) char smem[16896 + 34304];
  unsigned short (*aT)[264] = reinterpret_cast<unsigned short(*)[264]>(smem);
  unsigned short (*fT)[536] = reinterpret_cast<unsigned short(*)[536]>(smem + 16896);
  float (*sT)[257] = reinterpret_cast<float(*)[257]>(smem);   // aliases aT/fT after GEMMs
  __shared__ float prs[32][4], prq[32][4];
  int t = threadIdx.x, w = t >> 6, l = t & 63;
  int lm = l & 15, lk = (l >> 4) << 3;
  int row0 = blockIdx.x * 32;
  for (int r = 0; r < 32; ++r) aT[r][t] = Ab[(size_t)(row0 + r) * E + t];
  __syncthreads();
  f32x4 zz = {0.f, 0.f, 0.f, 0.f};
  f32x4 acc2[2][4];
  #pragma unroll
  for (int mt = 0; mt < 2; ++mt) for (int nt = 0; nt < 4; ++nt) acc2[mt][nt] = zz;
  for (int h = 0; h < 2; ++h) {
    // GEMM1: 32x256 @ 256x512 slice of Wi
    f32x4 acc1[2][8];
    #pragma unroll
    for (int mt = 0; mt < 2; ++mt) for (int nt = 0; nt < 8; ++nt) acc1[mt][nt] = zz;
    for (int kc = 0; kc < 8; ++kc) {
      bf16x8 a0 = *(const bf16x8*)&aT[lm][kc * 32 + lk];
      bf16x8 a1 = *(const bf16x8*)&aT[16 + lm][kc * 32 + lk];
      #pragma unroll
      for (int nt = 0; nt < 8; ++nt) {
        int n = h * 512 + w * 128 + nt * 16 + lm;
        bf16x8 bfr = *(const bf16x8*)&WiT[(size_t)n * 256 + kc * 32 + lk];
        acc1[0][nt] = mfma16(a0, bfr, acc1[0][nt]);
        acc1[1][nt] = mfma16(a1, bfr, acc1[1][nt]);
      }
    }
    // gelu -> fT (bf16)
    #pragma unroll
    for (int nt = 0; nt < 8; ++nt) {
      int cl = w * 128 + nt * 16 + lm;
      float bib = bi[h * 512 + cl];
      #pragma unroll
      for (int mt = 0; mt < 2; ++mt)
        #pragma unroll
        for (int r = 0; r < 4; ++r) {
          int row = mt * 16 + ((l >> 4) << 2) + r;
          float x = acc1[mt][nt][r] + bib;
          float ge = 0.5f * x * (1.f + erff(x * 0.70710678118654752f));
          fT[row][cl] = f2bf(ge);
        }
    }
    __syncthreads();
    // GEMM2: 32x512 @ 512x256 slice of Wf (accumulate)
    for (int kc = 0; kc < 16; ++kc) {
      bf16x8 f0 = *(const bf16x8*)&fT[lm][kc * 32 + lk];
      bf16x8 f1 = *(const bf16x8*)&fT[16 + lm][kc * 32 + lk];
      #pragma unroll
      for (int nt = 0; nt < 4; ++nt) {
        int n = w * 64 + nt * 16 + lm;
        bf16x8 bfr = *(const bf16x8*)&WfT[(size_t)n * 1024 + h * 512 + kc * 32 + lk];
        acc2[0][nt] = mfma16(f0, bfr, acc2[0][nt]);
        acc2[1][nt] = mfma16(f1, bfr, acc2[1][nt]);
      }
    }
    __syncthreads();
  }
  // bias + residual -> sT (aliases aT/fT; all reads done, synced)
  #pragma unroll
  for (int nt = 0; nt < 4; ++nt) {
    int col = w * 64 + nt * 16 + lm;
    float bb = bfv[col];
    #pragma unroll
    for (int mt = 0; mt < 2; ++mt)
      #pragma unroll
      for (int r = 0; r < 4; ++r) {
        int row = mt * 16 + ((l >> 4) << 2) + r;
        sT[row][col] = acc2[mt][nt][r] + bb + Res[(size_t)(row0 + row) * E + col];
      }
  }
  __syncthreads();
  int wid = t >> 6, lane = t & 63;
  float vcache[32];
  for (int r = 0; r < 32; ++r) {
    float v = sT[r][t];
    vcache[r] = v;
    float s = v, q = v * v;
    #pragma unroll
    for (int o = 32; o > 0; o >>= 1) { s += __shfl_down(s, o); q += __shfl_down(q, o); }
    if (lane == 0) { prs[r][wid] = s; prq[r][wid] = q; }
  }
  __syncthreads();
  #pragma unroll
  for (int r = 0; r < 32; ++r) {
    float Sv = prs[r][0] + prs[r][1] + prs[r][2] + prs[r][3];
    float Qv = prq[r][0] + prq[r][1] + prq[r][2] + prq[r][3];
    float m = Sv * (1.f / E), var = Qv * (1.f / E) - m * m;
    float val = (vcache[r] - m) * rsqrtf(var + 1e-12f) * g[t] + bvec[t];
    int gr = row0 + r;
    if (gr < split) out0[(size_t)gr * E + t] = val;
    else            out1[(size_t)(gr - split) * E + t] = val;
  }
}

// ---------------- agg (fp32) ----------------
__global__ __launch_bounds__(256) void agg_kernel(
    const float* __restrict__ hbase, int hstride,
    const float* __restrict__ p1, const float* __restrict__ p2,
    const float* __restrict__ Wagg, const float* __restrict__ bagg,
    float* __restrict__ outp) {
  __shared__ float pv[768];
  __shared__ float tmp4[4];
  int b = blockIdx.x, t = threadIdx.x;
  float x = hbase[(size_t)b * hstride + 4 * E + t];
  float n2 = block_sum256(x * x, tmp4);
  pv[t] = x / fmaxf(sqrtf(n2), 1e-12f);
  pv[256 + t] = p1[b * E + t];
  pv[512 + t] = p2[b * E + t];
  __syncthreads();
  float y = bagg[t];
  for (int u = 0; u < 768; ++u) y = fmaf(pv[u], Wagg[u * E + t], y);
  y = fmaxf(y, 0.f);
  float n3 = block_sum256(y * y, tmp4);
  outp[b * E + t] = y / fmaxf(sqrtf(n3), 1e-12f);
}

// ---------------- build iter-1 input (fp32 + bf16) ----------------
__global__ __launch_bounds__(256) void build_h2_kernel(
    const float* __restrict__ qe, const float* __restrict__ ke,
    const float* __restrict__ de, const float* __restrict__ ce,
    const float* __restrict__ agg0, const float* __restrict__ h1n0,
    float* __restrict__ h2f, unsigned short* __restrict__ h2b) {
  int b = blockIdx.x, t = threadIdx.x;
  size_t eb = (size_t)(b * 64) * E + t;
  size_t ob = (size_t)b * (SEQ * E);
  float v;
  v = qe[eb];            h2f[ob + 0 * E + t] = v; h2b[ob + 0 * E + t] = f2bf(v);
  v = ke[eb];            h2f[ob + 1 * E + t] = v; h2b[ob + 1 * E + t] = f2bf(v);
  v = de[eb];            h2f[ob + 2 * E + t] = v; h2b[ob + 2 * E + t] = f2bf(v);
  v = ce[eb];            h2f[ob + 3 * E + t] = v; h2b[ob + 3 * E + t] = f2bf(v);
  v = agg0[b * E + t];   h2f[ob + 4 * E + t] = v; h2b[ob + 4 * E + t] = f2bf(v);
  for (int s = 5; s < SEQ; ++s) {
    v = h1n0[ob + s * E + t];
    h2f[ob + s * E + t] = v; h2b[ob + s * E + t] = f2bf(v);
  }
}

// ---------------- final output ----------------
__global__ __launch_bounds__(256) void out_kernel(
    const float* __restrict__ h1n0, const float* __restrict__ agg0,
    const float* __restrict__ h2, const float* __restrict__ agg1,
    float* __restrict__ outp) {
  int b = blockIdx.x, t = threadIdx.x;
  size_t ob = (size_t)b * (SEQ * E);
  float s1v = agg0[b * E + t];
  float s2v = agg1[b * E + t];
  for (int s = 5; s < SEQ; ++s) { s1v += h1n0[ob + s * E + t]; s2v += h2[ob + s * E + t]; }
  outp[b * E + t] = 0.5f * (s1v + s2v) * (1.f / 28.f);
}

extern "C" void kernel_launch(void* const* d_in, const int* in_sizes, int n_in,
                              void* d_out, int out_size, void* d_ws, size_t ws_size,
                              hipStream_t stream) {
  (void)in_sizes; (void)n_in; (void)out_size;
  const float* hidden = (const float*)d_in[1];
  const float* amask  = (const float*)d_in[2];
  const float* qemb   = (const float*)d_in[3];
  const float* kemb   = (const float*)d_in[4];
  const float* demb   = (const float*)d_in[5];
  const float* cemb   = (const float*)d_in[6];
  const float* uop    = (const float*)d_in[7];
  const float* iop    = (const float*)d_in[8];
  const float* Wq = (const float*)d_in[9];  const float* bq = (const float*)d_in[10];
  const float* Wk = (const float*)d_in[11]; const float* bk = (const float*)d_in[12];
  const float* Wv = (const float*)d_in[13]; const float* bv = (const float*)d_in[14];
  const float* Wo = (const float*)d_in[15]; const float* bo = (const float*)d_in[16];
  const float* g1 = (const float*)d_in[17]; const float* b1 = (const float*)d_in[18];
  const float* Wi = (const float*)d_in[19]; const float* bi = (const float*)d_in[20];
  const float* Wf = (const float*)d_in[21]; const float* bf = (const float*)d_in[22];
  const float* g2 = (const float*)d_in[23]; const float* b2 = (const float*)d_in[24];
  const float* Wagg = (const float*)d_in[25]; const float* bagg = (const float*)d_in[26];
  const float* Wd1 = (const float*)d_in[27]; const float* bd1 = (const float*)d_in[28];
  const float* l1g = (const float*)d_in[29]; const float* l1b = (const float*)d_in[30];
  const float* Wd2 = (const float*)d_in[31]; const float* bd2 = (const float*)d_in[32];
  const float* l2g = (const float*)d_in[33]; const float* l2b = (const float*)d_in[34];

  // ---- workspace carve ----
  char* cur = (char*)d_ws;
  auto alloc_us = [&](size_t n) { unsigned short* p = (unsigned short*)cur; cur += ((n * 2 + 255) & ~(size_t)255); return p; };
  auto alloc_f  = [&](size_t n) { float* p = (float*)cur; cur += ((n * 4 + 255) & ~(size_t)255); return p; };
  unsigned short* wqt = alloc_us(131072);
  unsigned short* wkt = alloc_us(131072);
  unsigned short* wvt = alloc_us(131072);
  unsigned short* wot = alloc_us(131072);
  unsigned short* wit = alloc_us(524288);
  unsigned short* wft = alloc_us(524288);
  unsigned short* ctx_all = alloc_us((size_t)10240 * 256);
  unsigned short* aALLb   = alloc_us((size_t)10240 * 256);
  unsigned short* Kf   = alloc_us((size_t)2048 * 256);
  unsigned short* Vf   = alloc_us((size_t)2048 * 256);
  unsigned short* qn0  = alloc_us((size_t)2048 * 256);
  unsigned short* h2inb = alloc_us((size_t)2048 * 256);
  unsigned short* q2b  = alloc_us((size_t)2048 * 256);
  unsigned short* k2b  = alloc_us((size_t)2048 * 256);
  unsigned short* v2b  = alloc_us((size_t)2048 * 256);
  unsigned short* ctx1 = alloc_us((size_t)2048 * 256);
  unsigned short* a2b  = alloc_us((size_t)2048 * 256);
  float* aALLf = alloc_f((size_t)10240 * 256);
  float* h101  = alloc_f((size_t)4096 * 2 * 256);
  float* h1n0  = alloc_f((size_t)2048 * 256);
  float* h2inf = alloc_f((size_t)2048 * 256);
  float* a2f   = alloc_f((size_t)2048 * 256);
  float* h2    = alloc_f((size_t)2048 * 256);
  float* p1_0  = alloc_f(64 * 256);
  float* p2_0  = alloc_f(64 * 256);
  float* p1_1  = alloc_f(64 * 256);
  float* p2_1  = alloc_f(64 * 256);
  float* agg0  = alloc_f(64 * 256);
  float* agg1  = alloc_f(64 * 256);
  if ((size_t)(cur - (char*)d_ws) > ws_size) return;

  // ---- weight prep ----
  wprep_kernel<<<dim3(256, 6, 2), 256, 0, stream>>>(Wq, Wk, Wv, Wo, Wi, Wf,
                                                    wqt, wkt, wvt, wot, wit, wft);

  // ================= iteration 0 =================
  prop_ln_kernel<<<64, 256, 0, stream>>>(qemb, nullptr, 0, uop, Wd1, bd1, l1g, l1b, p1_0, 0);
  prop_ln_kernel<<<64, 256, 0, stream>>>(kemb, nullptr, 1, iop, Wd2, bd2, l2g, l2b, p2_0, 1);

  seq_attn_mfma<<<4096, 256, 0, stream>>>(hidden, wqt, bq, wkt, bk, wvt, bv,
                                          amask, ctx_all, Kf, Vf);
  gemm_bias_kernel<<<64, 256, 0, stream>>>(hidden, wqt, bq, qn0);
  attnf_kernel<<<dim3(64, 4), 256, 0, stream>>>(qn0, Kf, Vf, ctx_all + (size_t)8192 * 256,
                                                amask, 1);
  gemm_ln_mfma<<<320, 256, 0, stream>>>(ctx_all, wot, bo, hidden, 3, g1, b1, aALLf, aALLb);
  ffn_mfma<<<320, 256, 0, stream>>>(aALLb, aALLf, wit, bi, wft, bf, g2, b2,
                                    h101, h1n0, 8192);
  agg_kernel<<<64, 256, 0, stream>>>(h1n0, SEQ * E, p1_0, p2_0, Wagg, bagg, agg0);

  // ================= iteration 1 =================
  prop_ln_kernel<<<64, 256, 0, stream>>>(qemb, h101, 0, uop, Wd1, bd1, l1g, l1b, p1_1, 0);
  prop_ln_kernel<<<64, 256, 0, stream>>>(kemb, h101, 1, iop, Wd2, bd2, l2g, l2b, p2_1, 1);
  build_h2_kernel<<<64, 256, 0, stream>>>(qemb, kemb, demb, cemb, agg0, h1n0, h2inf, h2inb);

  qkv3_kernel<<<64, 256, 0, stream>>>(h2inb,
                                      wqt + 65536, bq + E, q2b,
                                      wkt + 65536, bk + E, k2b,
                                      wvt + 65536, bv + E, v2b);
  attnf_kernel<<<dim3(64, 4), 256, 0, stream>>>(q2b, k2b, v2b, ctx1, amask, 0);
  gemm_ln_mfma<<<64, 256, 0, stream>>>(ctx1, wot + 65536, bo + E, h2inf, 0,
                                       g1 + E, b1 + E, a2f, a2b);
  ffn_mfma<<<64, 256, 0, stream>>>(a2b, a2f, wit + 262144, bi + FF, wft + 262144, bf + E,
                                   g2 + E, b2 + E, h2, h2, 1 << 30);
  agg_kernel<<<64, 256, 0, stream>>>(h2, SEQ * E, p1_1, p2_1,
                                     Wagg + (size_t)768 * E, bagg + E, agg1);

  out_kernel<<<64, 256, 0, stream>>>(h1n0, agg0, h2, agg1, (float*)d_out);
}

// Round 4
// 604.084 us; speedup vs baseline: 9.7826x; 1.2799x over previous
//
#include <hip/hip_runtime.h>
#include <math.h>

#define E 256
#define SEQ 32
#define FF 1024
#define NEG_MASK -10000.0f

typedef __attribute__((ext_vector_type(8))) short bf16x8;
typedef __attribute__((ext_vector_type(4))) short s16x4;
typedef __attribute__((ext_vector_type(4))) float f32x4;

__device__ __forceinline__ float bf2f(unsigned short u) {
  unsigned v = ((unsigned)u) << 16; float f; __builtin_memcpy(&f, &v, 4); return f;
}
__device__ __forceinline__ unsigned short f2bf(float f) {
  unsigned u; __builtin_memcpy(&u, &f, 4);
  unsigned r = (u + 0x7fffu + ((u >> 16) & 1u)) >> 16;
  return (unsigned short)r;
}
__device__ __forceinline__ s16x4 f2bf4(float4 v) {
  s16x4 r;
  r[0] = (short)f2bf(v.x); r[1] = (short)f2bf(v.y);
  r[2] = (short)f2bf(v.z); r[3] = (short)f2bf(v.w);
  return r;
}
__device__ __forceinline__ f32x4 mfma16(bf16x8 a, bf16x8 b, f32x4 c) {
  return __builtin_amdgcn_mfma_f32_16x16x32_bf16(a, b, c, 0, 0, 0);
}
__device__ __forceinline__ float block_sum256(float v, float* tmp4) {
  #pragma unroll
  for (int o = 32; o > 0; o >>= 1) v += __shfl_down(v, o);
  int wid = threadIdx.x >> 6, lane = threadIdx.x & 63;
  if (lane == 0) tmp4[wid] = v;
  __syncthreads();
  float r = tmp4[0] + tmp4[1] + tmp4[2] + tmp4[3];
  __syncthreads();
  return r;
}

// ---------------- weight prep: fp32 W[k][n] -> bf16 Wt[n][k], per layer ----------------
__global__ __launch_bounds__(256) void wprep_kernel(
    const float* __restrict__ Wq, const float* __restrict__ Wk,
    const float* __restrict__ Wv, const float* __restrict__ Wo,
    const float* __restrict__ Wi, const float* __restrict__ Wf,
    unsigned short* wqt, unsigned short* wkt, unsigned short* wvt,
    unsigned short* wot, unsigned short* wit, unsigned short* wft) {
  int type = blockIdx.y, l = blockIdx.z, t = threadIdx.x;
  const float* src; unsigned short* dst; int Kd, Nd;
  switch (type) {
    case 0: src = Wq + (size_t)l * 65536; dst = wqt + (size_t)l * 65536; Kd = 256; Nd = 256; break;
    case 1: src = Wk + (size_t)l * 65536; dst = wkt + (size_t)l * 65536; Kd = 256; Nd = 256; break;
    case 2: src = Wv + (size_t)l * 65536; dst = wvt + (size_t)l * 65536; Kd = 256; Nd = 256; break;
    case 3: src = Wo + (size_t)l * 65536; dst = wot + (size_t)l * 65536; Kd = 256; Nd = 256; break;
    case 4: src = Wi + (size_t)l * 262144; dst = wit + (size_t)l * 262144; Kd = 256; Nd = 1024; break;
    default: src = Wf + (size_t)l * 262144; dst = wft + (size_t)l * 262144; Kd = 1024; Nd = 256; break;
  }
  int ntn = Nd >> 5;
  if (blockIdx.x >= (unsigned)((Kd >> 5) * ntn)) return;
  int k0 = (blockIdx.x / ntn) << 5, n0 = (blockIdx.x % ntn) << 5;
  __shared__ float tile[32][33];
  #pragma unroll
  for (int i = 0; i < 4; ++i) {
    int p = i * 256 + t; int kr = p >> 5, nc = p & 31;
    tile[kr][nc] = src[(size_t)(k0 + kr) * Nd + n0 + nc];
  }
  __syncthreads();
  #pragma unroll
  for (int i = 0; i < 4; ++i) {
    int p = i * 256 + t; int nr = p >> 5, kc = p & 31;
    dst[(size_t)(n0 + nr) * Kd + k0 + kc] = f2bf(tile[kc][nr]);
  }
}

// ---------------- sparse prop + W_d + LN; grid (64, 2): y selects q/k variant ----------------
__global__ __launch_bounds__(256) void prop_ln_kernel(
    const float* __restrict__ emb_q, const float* __restrict__ emb_k,
    const float* snq,
    const float* __restrict__ uop, const float* __restrict__ iop,
    const float* __restrict__ Wd1, const float* __restrict__ bd1,
    const float* __restrict__ g1v, const float* __restrict__ b1v,
    const float* __restrict__ Wd2, const float* __restrict__ bd2,
    const float* __restrict__ g2v, const float* __restrict__ b2v,
    float* __restrict__ out1, float* __restrict__ out2) {
  int sel = blockIdx.y;
  const float* emb = sel ? emb_k : emb_q;
  const float* op  = sel ? iop : uop;
  const float* Wd  = sel ? Wd2 : Wd1;
  const float* bd  = sel ? bd2 : bd1;
  const float* g   = sel ? g2v : g1v;
  const float* bvec= sel ? b2v : b1v;
  float* outp      = sel ? out2 : out1;
  int row = sel;
  __shared__ float t0s[64][E];
  __shared__ float s1[16 * E];
  __shared__ float s2[16 * E];
  __shared__ float wv[64];
  __shared__ int gi[64];
  __shared__ float t2row[E];
  __shared__ float tmp4[4];
  int b = blockIdx.x, e = threadIdx.x;
  if (e < 64) {
    wv[e] = op[(b * 64 + e) * 2 + 1];
    gi[e] = (int)op[(b * 64 + e) * 2 + 0];
  }
  for (int gg = 0; gg < 16; ++gg) { s1[gg * E + e] = 0.f; s2[gg * E + e] = 0.f; }
  for (int n = 0; n < 64; ++n) {
    float t0 = 0.5f * emb[(size_t)(b * 64 + n) * E + e];
    if (snq) t0 += snq[((size_t)(b * 64 + n) * 2 + sel) * E + e];
    t0s[n][e] = t0;
  }
  __syncthreads();
  for (int n = 0; n < 64; ++n) s1[gi[n] * E + e] += wv[n] * t0s[n][e];
  for (int n = 0; n < 64; ++n) {
    float t1 = wv[n] * s1[gi[n] * E + e] + 0.1f * t0s[n][e];
    s2[gi[n] * E + e] += wv[n] * t1;
  }
  float t2 = wv[row] * s2[gi[row] * E + e] + 0.1f * t0s[row][e];
  t2row[e] = t2;
  __syncthreads();
  float y = bd[e];
  for (int k = 0; k < E; ++k) y = fmaf(t2row[k], Wd[k * E + e], y);
  float ssum = block_sum256(y, tmp4);
  float qsum = block_sum256(y * y, tmp4);
  float m = ssum * (1.f / E);
  float var = qsum * (1.f / E) - m * m;
  outp[b * E + e] = (y - m) * rsqrtf(var + 1e-12f) * g[e] + bvec[e];
}

// ---------------- fused per-seq: K+Q proj (merged), MFMA scores, softmax, V proj, PV ----------------
__global__ __launch_bounds__(256, 4) void seq_attn_mfma(
    const float* __restrict__ hidden,
    const unsigned short* __restrict__ wqt, const float* __restrict__ bq,
    const unsigned short* __restrict__ wkt, const float* __restrict__ bk,
    const unsigned short* __restrict__ wvt, const float* __restrict__ bv,
    const float* __restrict__ mask, unsigned short* __restrict__ ctx_all,
    unsigned short* __restrict__ Kf, unsigned short* __restrict__ Vf) {
  __shared__ __align__(16) unsigned short aT[32][264];
  __shared__ __align__(16) unsigned short kvb[32][272];
  __shared__ __align__(16) unsigned short qs16[2][264];
  __shared__ float pr[4][2][36];
  int a = blockIdx.x, t = threadIdx.x;
  int w = t >> 6, l = t & 63;
  int lm = l & 15, lkq = l >> 4, lk = lkq << 3;
  size_t hb = (size_t)a * (SEQ * E);
  // stage hidden -> bf16 aT (float4 loads, 8B LDS writes)
  #pragma unroll
  for (int i = 0; i < 8; ++i) {
    int p = i * 256 + t; int row = p >> 6, c4 = (p & 63) << 2;
    float4 v = *(const float4*)&hidden[hb + row * E + c4];
    *(s16x4*)&aT[row][c4] = f2bf4(v);
  }
  __syncthreads();
  bool isn0 = ((a & 63) == 0);
  int nb = a >> 6;
  f32x4 zz = {0.f, 0.f, 0.f, 0.f};
  // ---- merged K (all rows) + Q (rows 0,1) projection, nt-major ----
  #pragma unroll
  for (int nt = 0; nt < 4; ++nt) {
    int ncol = w * 64 + nt * 16 + lm;
    const unsigned short* bkrow = &wkt[(size_t)ncol * 256 + lk];
    const unsigned short* bqrow = &wqt[(size_t)ncol * 256 + lk];
    bf16x8 bk8[8], bq8[8];
    #pragma unroll
    for (int kc = 0; kc < 8; ++kc) bk8[kc] = *(const bf16x8*)(bkrow + kc * 32);
    #pragma unroll
    for (int kc = 0; kc < 8; ++kc) bq8[kc] = *(const bf16x8*)(bqrow + kc * 32);
    f32x4 ak0 = zz, ak1 = zz, aq = zz;
    #pragma unroll
    for (int kc = 0; kc < 8; ++kc) {
      bf16x8 a0 = *(const bf16x8*)&aT[lm][kc * 32 + lk];
      bf16x8 a1 = *(const bf16x8*)&aT[16 + lm][kc * 32 + lk];
      ak0 = mfma16(a0, bk8[kc], ak0);
      ak1 = mfma16(a1, bk8[kc], ak1);
      aq  = mfma16(a0, bq8[kc], aq);
    }
    float bb = bk[ncol];
    #pragma unroll
    for (int r = 0; r < 4; ++r) {
      int rw = (lkq << 2) + r;
      float v0 = ak0[r] + bb, v1 = ak1[r] + bb;
      kvb[rw][ncol] = f2bf(v0);
      kvb[16 + rw][ncol] = f2bf(v1);
      if (isn0) {
        Kf[((size_t)nb * 32 + rw) * 256 + ncol] = f2bf(v0);
        Kf[((size_t)nb * 32 + 16 + rw) * 256 + ncol] = f2bf(v1);
      }
    }
    if (lkq == 0) {
      float bqv = bq[ncol];
      qs16[0][ncol] = f2bf(aq[0] + bqv);
      qs16[1][ncol] = f2bf(aq[1] + bqv);
    }
  }
  __syncthreads();
  // ---- QK^T scores via MFMA (head = wave), softmax in 16-lane group ----
  {
    f32x4 sc0 = zz, sc1 = zz;
    #pragma unroll
    for (int kc2 = 0; kc2 < 2; ++kc2) {
      bf16x8 aq = *(const bf16x8*)&qs16[lm & 1][w * 64 + kc2 * 32 + lk];
      bf16x8 b0 = *(const bf16x8*)&kvb[lm][w * 64 + kc2 * 32 + lk];
      bf16x8 b1 = *(const bf16x8*)&kvb[16 + lm][w * 64 + kc2 * 32 + lk];
      sc0 = mfma16(aq, b0, sc0);
      sc1 = mfma16(aq, b1, sc1);
    }
    // valid rows qr=0,1 live in lanes lkq==0, regs r=0,1; cols: tt=lm (sc0), 16+lm (sc1)
    float mv0 = (lm < 4) ? NEG_MASK : mask[(size_t)a * SEQ + lm];
    float mv1 = mask[(size_t)a * SEQ + 16 + lm];
    #pragma unroll
    for (int r = 0; r < 2; ++r) {
      float s0 = sc0[r] * 0.125f + mv0;
      float s1 = sc1[r] * 0.125f + mv1;
      float mx = fmaxf(s0, s1);
      mx = fmaxf(mx, __shfl_xor(mx, 1));
      mx = fmaxf(mx, __shfl_xor(mx, 2));
      mx = fmaxf(mx, __shfl_xor(mx, 4));
      mx = fmaxf(mx, __shfl_xor(mx, 8));
      float e0 = expf(s0 - mx), e1 = expf(s1 - mx);
      float se = e0 + e1;
      se += __shfl_xor(se, 1); se += __shfl_xor(se, 2);
      se += __shfl_xor(se, 4); se += __shfl_xor(se, 8);
      float inv = 1.f / se;
      if (lkq == 0) {
        pr[w][r][lm] = e0 * inv;
        pr[w][r][16 + lm] = e1 * inv;
      }
    }
  }
  __syncthreads();   // K reads done; pr visible; kvb reusable for V
  // ---- V projection (nt-major), overwrites kvb ----
  #pragma unroll
  for (int nt = 0; nt < 4; ++nt) {
    int ncol = w * 64 + nt * 16 + lm;
    const unsigned short* bvrow = &wvt[(size_t)ncol * 256 + lk];
    bf16x8 bv8[8];
    #pragma unroll
    for (int kc = 0; kc < 8; ++kc) bv8[kc] = *(const bf16x8*)(bvrow + kc * 32);
    f32x4 av0 = zz, av1 = zz;
    #pragma unroll
    for (int kc = 0; kc < 8; ++kc) {
      bf16x8 a0 = *(const bf16x8*)&aT[lm][kc * 32 + lk];
      bf16x8 a1 = *(const bf16x8*)&aT[16 + lm][kc * 32 + lk];
      av0 = mfma16(a0, bv8[kc], av0);
      av1 = mfma16(a1, bv8[kc], av1);
    }
    float bb = bv[ncol];
    #pragma unroll
    for (int r = 0; r < 4; ++r) {
      int rw = (lkq << 2) + r;
      float v0 = av0[r] + bb, v1 = av1[r] + bb;
      kvb[rw][ncol] = f2bf(v0);
      kvb[16 + rw][ncol] = f2bf(v1);
      if (isn0) {
        Vf[((size_t)nb * 32 + rw) * 256 + ncol] = f2bf(v0);
        Vf[((size_t)nb * 32 + 16 + rw) * 256 + ncol] = f2bf(v1);
      }
    }
  }
  __syncthreads();
  // ---- PV rows 0,1 (thread t = output col; head = t>>6) ----
  {
    float o0 = 0.f, o1 = 0.f;
    #pragma unroll
    for (int tt = 0; tt < 32; ++tt) {
      float vv = bf2f(kvb[tt][t]);
      o0 = fmaf(pr[w][0][tt], vv, o0);
      o1 = fmaf(pr[w][1][tt], vv, o1);
    }
    ctx_all[((size_t)a * 2 + 0) * E + t] = f2bf(o0);
    ctx_all[((size_t)a * 2 + 1) * E + t] = f2bf(o1);
  }
}

// ---------------- Q projection for n0 rows (gathered A), nt-major ----------------
__global__ __launch_bounds__(256) void gemm_bias_kernel(
    const float* __restrict__ Af, const unsigned short* __restrict__ Bt,
    const float* __restrict__ bias, unsigned short* __restrict__ outb) {
  __shared__ __align__(16) unsigned short aT[32][264];
  int t = threadIdx.x, w = t >> 6, l = t & 63;
  int lm = l & 15, lkq = l >> 4, lk = lkq << 3;
  int row0 = blockIdx.x * 32;
  #pragma unroll
  for (int i = 0; i < 8; ++i) {
    int p = i * 256 + t; int row = p >> 6, c4 = (p & 63) << 2;
    int gr = row0 + row;
    int src = ((gr >> 5) << 11) + (gr & 31);
    float4 v = *(const float4*)&Af[(size_t)src * E + c4];
    *(s16x4*)&aT[row][c4] = f2bf4(v);
  }
  __syncthreads();
  f32x4 zz = {0.f, 0.f, 0.f, 0.f};
  #pragma unroll
  for (int nt = 0; nt < 4; ++nt) {
    int ncol = w * 64 + nt * 16 + lm;
    const unsigned short* brow = &Bt[(size_t)ncol * 256 + lk];
    bf16x8 b8[8];
    #pragma unroll
    for (int kc = 0; kc < 8; ++kc) b8[kc] = *(const bf16x8*)(brow + kc * 32);
    f32x4 c0 = zz, c1 = zz;
    #pragma unroll
    for (int kc = 0; kc < 8; ++kc) {
      bf16x8 a0 = *(const bf16x8*)&aT[lm][kc * 32 + lk];
      bf16x8 a1 = *(const bf16x8*)&aT[16 + lm][kc * 32 + lk];
      c0 = mfma16(a0, b8[kc], c0);
      c1 = mfma16(a1, b8[kc], c1);
    }
    float bb = bias[ncol];
    #pragma unroll
    for (int r = 0; r < 4; ++r) {
      int rw = (lkq << 2) + r;
      outb[(size_t)(row0 + rw) * E + ncol] = f2bf(c0[r] + bb);
      outb[(size_t)(row0 + 16 + rw) * E + ncol] = f2bf(c1[r] + bb);
    }
  }
}

// ---------------- 3-in-1 MFMA QKV (A bf16 contiguous), nt-major ----------------
__global__ __launch_bounds__(256) void qkv3_kernel(
    const unsigned short* __restrict__ Ab,
    const unsigned short* bt0, const float* b0, unsigned short* o0,
    const unsigned short* bt1, const float* b1, unsigned short* o1,
    const unsigned short* bt2, const float* b2, unsigned short* o2) {
  __shared__ __align__(16) unsigned short aT[32][264];
  int t = threadIdx.x, w = t >> 6, l = t & 63;
  int lm = l & 15, lkq = l >> 4, lk = lkq << 3;
  int row0 = blockIdx.x * 32;
  #pragma unroll
  for (int i = 0; i < 8; ++i) {
    int p = i * 256 + t; int row = p >> 6, c4 = (p & 63) << 2;
    *(s16x4*)&aT[row][c4] = *(const s16x4*)&Ab[(size_t)(row0 + row) * E + c4];
  }
  __syncthreads();
  const unsigned short* bts[3] = {bt0, bt1, bt2};
  const float* bss[3] = {b0, b1, b2};
  unsigned short* oss[3] = {o0, o1, o2};
  f32x4 zz = {0.f, 0.f, 0.f, 0.f};
  for (int m = 0; m < 3; ++m) {
    #pragma unroll
    for (int nt = 0; nt < 4; ++nt) {
      int ncol = w * 64 + nt * 16 + lm;
      const unsigned short* brow = &bts[m][(size_t)ncol * 256 + lk];
      bf16x8 b8[8];
      #pragma unroll
      for (int kc = 0; kc < 8; ++kc) b8[kc] = *(const bf16x8*)(brow + kc * 32);
      f32x4 c0 = zz, c1 = zz;
      #pragma unroll
      for (int kc = 0; kc < 8; ++kc) {
        bf16x8 a0 = *(const bf16x8*)&aT[lm][kc * 32 + lk];
        bf16x8 a1 = *(const bf16x8*)&aT[16 + lm][kc * 32 + lk];
        c0 = mfma16(a0, b8[kc], c0);
        c1 = mfma16(a1, b8[kc], c1);
      }
      float bb = bss[m][ncol];
      #pragma unroll
      for (int r = 0; r < 4; ++r) {
        int rw = (lkq << 2) + r;
        oss[m][(size_t)(row0 + rw) * E + ncol] = f2bf(c0[r] + bb);
        oss[m][(size_t)(row0 + 16 + rw) * E + ncol] = f2bf(c1[r] + bb);
      }
    }
  }
}

// ---------------- full attention (bf16 in/out), compact 64-seq buffers ----------------
__global__ __launch_bounds__(256) void attnf_kernel(
    const unsigned short* __restrict__ Q, const unsigned short* __restrict__ K,
    const unsigned short* __restrict__ V, unsigned short* __restrict__ CTX,
    const float* __restrict__ mask, int set4) {
  int b = blockIdx.x, h = blockIdx.y, t = threadIdx.x;
  __shared__ float qsh[32][65], ksh[32][65], vsh[32][65];
  __shared__ float pr[32][33];
  size_t base = (size_t)b * (SEQ * E) + h * 64;
  for (int i = 0; i < 8; ++i) {
    int p = i * 256 + t; int s = p >> 6, d = p & 63;
    qsh[s][d] = bf2f(Q[base + s * E + d]);
    ksh[s][d] = bf2f(K[base + s * E + d]);
    vsh[s][d] = bf2f(V[base + s * E + d]);
  }
  __syncthreads();
  for (int i = 0; i < 4; ++i) {
    int p = i * 256 + t; int s = p >> 5, tt = p & 31;
    float acc = 0.f;
    #pragma unroll
    for (int d = 0; d < 64; ++d) acc = fmaf(qsh[s][d], ksh[tt][d], acc);
    float mv = mask[(size_t)b * 2048 + tt];
    if (set4 && tt < 4) mv = NEG_MASK;
    pr[s][tt] = acc * 0.125f + mv;
  }
  __syncthreads();
  int rrow = t >> 3, l8 = t & 7;
  float vals[4];
  float mx = -1e30f;
  #pragma unroll
  for (int ii = 0; ii < 4; ++ii) { vals[ii] = pr[rrow][l8 + ii * 8]; mx = fmaxf(mx, vals[ii]); }
  mx = fmaxf(mx, __shfl_xor(mx, 1));
  mx = fmaxf(mx, __shfl_xor(mx, 2));
  mx = fmaxf(mx, __shfl_xor(mx, 4));
  float se = 0.f;
  #pragma unroll
  for (int ii = 0; ii < 4; ++ii) { vals[ii] = expf(vals[ii] - mx); se += vals[ii]; }
  se += __shfl_xor(se, 1); se += __shfl_xor(se, 2); se += __shfl_xor(se, 4);
  float inv = 1.f / se;
  #pragma unroll
  for (int ii = 0; ii < 4; ++ii) pr[rrow][l8 + ii * 8] = vals[ii] * inv;
  __syncthreads();
  for (int i = 0; i < 8; ++i) {
    int p = i * 256 + t; int s = p >> 6, d = p & 63;
    float acc = 0.f;
    #pragma unroll
    for (int tt = 0; tt < SEQ; ++tt) acc = fmaf(pr[s][tt], vsh[tt][d], acc);
    CTX[base + s * E + d] = f2bf(acc);
  }
}

__device__ __forceinline__ int map_res(int mode, int gr) {
  if (mode == 0) return gr;
  if (gr < 8192) return ((gr >> 1) << 5) + (gr & 1);
  int rr = gr - 8192;
  return ((rr >> 5) << 11) + (rr & 31);
}

// ---------------- MFMA GEMM(K=256) + bias + residual + LN -> fp32 + bf16 ----------------
__global__ __launch_bounds__(256) void gemm_ln_mfma(
    const unsigned short* __restrict__ Ab, const unsigned short* __restrict__ Bt,
    const float* __restrict__ bias, const float* __restrict__ Res, int resmode,
    const float* __restrict__ g, const float* __restrict__ bvec,
    float* __restrict__ outf, unsigned short* __restrict__ outb) {
  __shared__ __align__(16) unsigned short aT[32][264];
  __shared__ float sT[32][257];
  __shared__ float prs[32][4], prq[32][4];
  int t = threadIdx.x, w = t >> 6, l = t & 63;
  int lm = l & 15, lkq = l >> 4, lk = lkq << 3;
  int row0 = blockIdx.x * 32;
  #pragma unroll
  for (int i = 0; i < 8; ++i) {
    int p = i * 256 + t; int row = p >> 6, c4 = (p & 63) << 2;
    *(s16x4*)&aT[row][c4] = *(const s16x4*)&Ab[(size_t)(row0 + row) * E + c4];
  }
  __syncthreads();
  f32x4 zz = {0.f, 0.f, 0.f, 0.f};
  #pragma unroll
  for (int nt = 0; nt < 4; ++nt) {
    int ncol = w * 64 + nt * 16 + lm;
    const unsigned short* brow = &Bt[(size_t)ncol * 256 + lk];
    bf16x8 b8[8];
    #pragma unroll
    for (int kc = 0; kc < 8; ++kc) b8[kc] = *(const bf16x8*)(brow + kc * 32);
    f32x4 c0 = zz, c1 = zz;
    #pragma unroll
    for (int kc = 0; kc < 8; ++kc) {
      bf16x8 a0 = *(const bf16x8*)&aT[lm][kc * 32 + lk];
      bf16x8 a1 = *(const bf16x8*)&aT[16 + lm][kc * 32 + lk];
      c0 = mfma16(a0, b8[kc], c0);
      c1 = mfma16(a1, b8[kc], c1);
    }
    float bb = bias[ncol];
    #pragma unroll
    for (int r = 0; r < 4; ++r) {
      int rw = (lkq << 2) + r;
      int rr0 = map_res(resmode, row0 + rw);
      int rr1 = map_res(resmode, row0 + 16 + rw);
      sT[rw][ncol] = c0[r] + bb + Res[(size_t)rr0 * E + ncol];
      sT[16 + rw][ncol] = c1[r] + bb + Res[(size_t)rr1 * E + ncol];
    }
  }
  __syncthreads();
  int wid = t >> 6, lane = t & 63;
  float vcache[32];
  for (int r = 0; r < 32; ++r) {
    float v = sT[r][t];
    vcache[r] = v;
    float s = v, q = v * v;
    #pragma unroll
    for (int o = 32; o > 0; o >>= 1) { s += __shfl_down(s, o); q += __shfl_down(q, o); }
    if (lane == 0) { prs[r][wid] = s; prq[r][wid] = q; }
  }
  __syncthreads();
  #pragma unroll
  for (int r = 0; r < 32; ++r) {
    float Sv = prs[r][0] + prs[r][1] + prs[r][2] + prs[r][3];
    float Qv = prq[r][0] + prq[r][1] + prq[r][2] + prq[r][3];
    float m = Sv * (1.f / E), var = Qv * (1.f / E) - m * m;
    float val = (vcache[r] - m) * rsqrtf(var + 1e-12f) * g[t] + bvec[t];
    outf[(size_t)(row0 + r) * E + t] = val;
    outb[(size_t)(row0 + r) * E + t] = f2bf(val);
  }
}

// ---------------- fused MFMA FFN: LN(gelu(A@Wi+bi)@Wf + bf + Res), nt-major ----------------
__global__ __launch_bounds__(256) void ffn_mfma(
    const unsigned short* __restrict__ Ab, const float* __restrict__ Res,
    const unsigned short* __restrict__ WiT, const float* __restrict__ bi,
    const unsigned short* __restrict__ WfT, const float* __restrict__ bfv,
    const float* __restrict__ g, const float* __restrict__ bvec,
    float* __restrict__ out0, float* __restrict__ out1, int split) {
  __shared__ __align__(16) char smem[16896 + 34304];
  unsigned short (*aT)[264] = reinterpret_cast<unsigned short(*)[264]>(smem);
  unsigned short (*fT)[536] = reinterpret_cast<unsigned short(*)[536]>(smem + 16896);
  float (*sT)[257] = reinterpret_cast<float(*)[257]>(smem);
  __shared__ float prs[32][4], prq[32][4];
  int t = threadIdx.x, w = t >> 6, l = t & 63;
  int lm = l & 15, lkq = l >> 4, lk = lkq << 3;
  int row0 = blockIdx.x * 32;
  #pragma unroll
  for (int i = 0; i < 8; ++i) {
    int p = i * 256 + t; int row = p >> 6, c4 = (p & 63) << 2;
    *(s16x4*)&aT[row][c4] = *(const s16x4*)&Ab[(size_t)(row0 + row) * E + c4];
  }
  __syncthreads();
  f32x4 zz = {0.f, 0.f, 0.f, 0.f};
  f32x4 acc2[2][4];
  #pragma unroll
  for (int mt = 0; mt < 2; ++mt)
    #pragma unroll
    for (int nt = 0; nt < 4; ++nt) acc2[mt][nt] = zz;
  for (int h = 0; h < 2; ++h) {
    // GEMM1: 32x256 @ 256x512 slice of Wi, gelu -> fT
    #pragma unroll
    for (int nt = 0; nt < 8; ++nt) {
      int n = h * 512 + w * 128 + nt * 16 + lm;
      const unsigned short* brow = &WiT[(size_t)n * 256 + lk];
      bf16x8 b8[8];
      #pragma unroll
      for (int kc = 0; kc < 8; ++kc) b8[kc] = *(const bf16x8*)(brow + kc * 32);
      f32x4 c0 = zz, c1 = zz;
      #pragma unroll
      for (int kc = 0; kc < 8; ++kc) {
        bf16x8 a0 = *(const bf16x8*)&aT[lm][kc * 32 + lk];
        bf16x8 a1 = *(const bf16x8*)&aT[16 + lm][kc * 32 + lk];
        c0 = mfma16(a0, b8[kc], c0);
        c1 = mfma16(a1, b8[kc], c1);
      }
      int cl = w * 128 + nt * 16 + lm;
      float bib = bi[h * 512 + cl];
      #pragma unroll
      for (int r = 0; r < 4; ++r) {
        int rw = (lkq << 2) + r;
        float x0 = c0[r] + bib;
        float x1 = c1[r] + bib;
        fT[rw][cl] = f2bf(0.5f * x0 * (1.f + erff(x0 * 0.70710678118654752f)));
        fT[16 + rw][cl] = f2bf(0.5f * x1 * (1.f + erff(x1 * 0.70710678118654752f)));
      }
    }
    __syncthreads();
    // GEMM2: 32x512 @ 512x256 slice of Wf (accumulate into acc2)
    #pragma unroll
    for (int nt = 0; nt < 4; ++nt) {
      int n = w * 64 + nt * 16 + lm;
      const unsigned short* brow = &WfT[(size_t)n * 1024 + h * 512 + lk];
      bf16x8 b16[16];
      #pragma unroll
      for (int kc = 0; kc < 16; ++kc) b16[kc] = *(const bf16x8*)(brow + kc * 32);
      #pragma unroll
      for (int kc = 0; kc < 16; ++kc) {
        bf16x8 f0 = *(const bf16x8*)&fT[lm][kc * 32 + lk];
        bf16x8 f1 = *(const bf16x8*)&fT[16 + lm][kc * 32 + lk];
        acc2[0][nt] = mfma16(f0, b16[kc], acc2[0][nt]);
        acc2[1][nt] = mfma16(f1, b16[kc], acc2[1][nt]);
      }
    }
    __syncthreads();
  }
  // bias + residual -> sT (aliases aT/fT; all reads done, synced)
  #pragma unroll
  for (int nt = 0; nt < 4; ++nt) {
    int col = w * 64 + nt * 16 + lm;
    float bb = bfv[col];
    #pragma unroll
    for (int r = 0; r < 4; ++r) {
      int rw = (lkq << 2) + r;
      sT[rw][col] = acc2[0][nt][r] + bb + Res[(size_t)(row0 + rw) * E + col];
      sT[16 + rw][col] = acc2[1][nt][r] + bb + Res[(size_t)(row0 + 16 + rw) * E + col];
    }
  }
  __syncthreads();
  int wid = t >> 6, lane = t & 63;
  float vcache[32];
  for (int r = 0; r < 32; ++r) {
    float v = sT[r][t];
    vcache[r] = v;
    float s = v, q = v * v;
    #pragma unroll
    for (int o = 32; o > 0; o >>= 1) { s += __shfl_down(s, o); q += __shfl_down(q, o); }
    if (lane == 0) { prs[r][wid] = s; prq[r][wid] = q; }
  }
  __syncthreads();
  #pragma unroll
  for (int r = 0; r < 32; ++r) {
    float Sv = prs[r][0] + prs[r][1] + prs[r][2] + prs[r][3];
    float Qv = prq[r][0] + prq[r][1] + prq[r][2] + prq[r][3];
    float m = Sv * (1.f / E), var = Qv * (1.f / E) - m * m;
    float val = (vcache[r] - m) * rsqrtf(var + 1e-12f) * g[t] + bvec[t];
    int gr = row0 + r;
    if (gr < split) out0[(size_t)gr * E + t] = val;
    else            out1[(size_t)(gr - split) * E + t] = val;
  }
}

// ---------------- agg (fp32) ----------------
__global__ __launch_bounds__(256) void agg_kernel(
    const float* __restrict__ hbase, int hstride,
    const float* __restrict__ p1, const float* __restrict__ p2,
    const float* __restrict__ Wagg, const float* __restrict__ bagg,
    float* __restrict__ outp) {
  __shared__ float pv[768];
  __shared__ float tmp4[4];
  int b = blockIdx.x, t = threadIdx.x;
  float x = hbase[(size_t)b * hstride + 4 * E + t];
  float n2 = block_sum256(x * x, tmp4);
  pv[t] = x / fmaxf(sqrtf(n2), 1e-12f);
  pv[256 + t] = p1[b * E + t];
  pv[512 + t] = p2[b * E + t];
  __syncthreads();
  float y = bagg[t];
  for (int u = 0; u < 768; ++u) y = fmaf(pv[u], Wagg[u * E + t], y);
  y = fmaxf(y, 0.f);
  float n3 = block_sum256(y * y, tmp4);
  outp[b * E + t] = y / fmaxf(sqrtf(n3), 1e-12f);
}

// ---------------- build iter-1 input (fp32 + bf16) ----------------
__global__ __launch_bounds__(256) void build_h2_kernel(
    const float* __restrict__ qe, const float* __restrict__ ke,
    const float* __restrict__ de, const float* __restrict__ ce,
    const float* __restrict__ agg0, const float* __restrict__ h1n0,
    float* __restrict__ h2f, unsigned short* __restrict__ h2b) {
  int b = blockIdx.x, t = threadIdx.x;
  size_t eb = (size_t)(b * 64) * E + t;
  size_t ob = (size_t)b * (SEQ * E);
  float v;
  v = qe[eb];            h2f[ob + 0 * E + t] = v; h2b[ob + 0 * E + t] = f2bf(v);
  v = ke[eb];            h2f[ob + 1 * E + t] = v; h2b[ob + 1 * E + t] = f2bf(v);
  v = de[eb];            h2f[ob + 2 * E + t] = v; h2b[ob + 2 * E + t] = f2bf(v);
  v = ce[eb];            h2f[ob + 3 * E + t] = v; h2b[ob + 3 * E + t] = f2bf(v);
  v = agg0[b * E + t];   h2f[ob + 4 * E + t] = v; h2b[ob + 4 * E + t] = f2bf(v);
  for (int s = 5; s < SEQ; ++s) {
    v = h1n0[ob + s * E + t];
    h2f[ob + s * E + t] = v; h2b[ob + s * E + t] = f2bf(v);
  }
}

// ---------------- final output ----------------
__global__ __launch_bounds__(256) void out_kernel(
    const float* __restrict__ h1n0, const float* __restrict__ agg0,
    const float* __restrict__ h2, const float* __restrict__ agg1,
    float* __restrict__ outp) {
  int b = blockIdx.x, t = threadIdx.x;
  size_t ob = (size_t)b * (SEQ * E);
  float s1v = agg0[b * E + t];
  float s2v = agg1[b * E + t];
  for (int s = 5; s < SEQ; ++s) { s1v += h1n0[ob + s * E + t]; s2v += h2[ob + s * E + t]; }
  outp[b * E + t] = 0.5f * (s1v + s2v) * (1.f / 28.f);
}

extern "C" void kernel_launch(void* const* d_in, const int* in_sizes, int n_in,
                              void* d_out, int out_size, void* d_ws, size_t ws_size,
                              hipStream_t stream) {
  (void)in_sizes; (void)n_in; (void)out_size;
  const float* hidden = (const float*)d_in[1];
  const float* amask  = (const float*)d_in[2];
  const float* qemb   = (const float*)d_in[3];
  const float* kemb   = (const float*)d_in[4];
  const float* demb   = (const float*)d_in[5];
  const float* cemb   = (const float*)d_in[6];
  const float* uop    = (const float*)d_in[7];
  const float* iop    = (const float*)d_in[8];
  const float* Wq = (const float*)d_in[9];  const float* bq = (const float*)d_in[10];
  const float* Wk = (const float*)d_in[11]; const float* bk = (const float*)d_in[12];
  const float* Wv = (const float*)d_in[13]; const float* bv = (const float*)d_in[14];
  const float* Wo = (const float*)d_in[15]; const float* bo = (const float*)d_in[16];
  const float* g1 = (const float*)d_in[17]; const float* b1 = (const float*)d_in[18];
  const float* Wi = (const float*)d_in[19]; const float* bi = (const float*)d_in[20];
  const float* Wf = (const float*)d_in[21]; const float* bf = (const float*)d_in[22];
  const float* g2 = (const float*)d_in[23]; const float* b2 = (const float*)d_in[24];
  const float* Wagg = (const float*)d_in[25]; const float* bagg = (const float*)d_in[26];
  const float* Wd1 = (const float*)d_in[27]; const float* bd1 = (const float*)d_in[28];
  const float* l1g = (const float*)d_in[29]; const float* l1b = (const float*)d_in[30];
  const float* Wd2 = (const float*)d_in[31]; const float* bd2 = (const float*)d_in[32];
  const float* l2g = (const float*)d_in[33]; const float* l2b = (const float*)d_in[34];

  // ---- workspace carve ----
  char* cur = (char*)d_ws;
  auto alloc_us = [&](size_t n) { unsigned short* p = (unsigned short*)cur; cur += ((n * 2 + 255) & ~(size_t)255); return p; };
  auto alloc_f  = [&](size_t n) { float* p = (float*)cur; cur += ((n * 4 + 255) & ~(size_t)255); return p; };
  unsigned short* wqt = alloc_us(131072);
  unsigned short* wkt = alloc_us(131072);
  unsigned short* wvt = alloc_us(131072);
  unsigned short* wot = alloc_us(131072);
  unsigned short* wit = alloc_us(524288);
  unsigned short* wft = alloc_us(524288);
  unsigned short* ctx_all = alloc_us((size_t)10240 * 256);
  unsigned short* aALLb   = alloc_us((size_t)10240 * 256);
  unsigned short* Kf   = alloc_us((size_t)2048 * 256);
  unsigned short* Vf   = alloc_us((size_t)2048 * 256);
  unsigned short* qn0  = alloc_us((size_t)2048 * 256);
  unsigned short* h2inb = alloc_us((size_t)2048 * 256);
  unsigned short* q2b  = alloc_us((size_t)2048 * 256);
  unsigned short* k2b  = alloc_us((size_t)2048 * 256);
  unsigned short* v2b  = alloc_us((size_t)2048 * 256);
  unsigned short* ctx1 = alloc_us((size_t)2048 * 256);
  unsigned short* a2b  = alloc_us((size_t)2048 * 256);
  float* aALLf = alloc_f((size_t)10240 * 256);
  float* h101  = alloc_f((size_t)4096 * 2 * 256);
  float* h1n0  = alloc_f((size_t)2048 * 256);
  float* h2inf = alloc_f((size_t)2048 * 256);
  float* a2f   = alloc_f((size_t)2048 * 256);
  float* h2    = alloc_f((size_t)2048 * 256);
  float* p1_0  = alloc_f(64 * 256);
  float* p2_0  = alloc_f(64 * 256);
  float* p1_1  = alloc_f(64 * 256);
  float* p2_1  = alloc_f(64 * 256);
  float* agg0  = alloc_f(64 * 256);
  float* agg1  = alloc_f(64 * 256);
  if ((size_t)(cur - (char*)d_ws) > ws_size) return;

  // ---- weight prep ----
  wprep_kernel<<<dim3(256, 6, 2), 256, 0, stream>>>(Wq, Wk, Wv, Wo, Wi, Wf,
                                                    wqt, wkt, wvt, wot, wit, wft);

  // ================= iteration 0 =================
  prop_ln_kernel<<<dim3(64, 2), 256, 0, stream>>>(qemb, kemb, nullptr, uop, iop,
                                                  Wd1, bd1, l1g, l1b, Wd2, bd2, l2g, l2b,
                                                  p1_0, p2_0);
  seq_attn_mfma<<<4096, 256, 0, stream>>>(hidden, wqt, bq, wkt, bk, wvt, bv,
                                          amask, ctx_all, Kf, Vf);
  gemm_bias_kernel<<<64, 256, 0, stream>>>(hidden, wqt, bq, qn0);
  attnf_kernel<<<dim3(64, 4), 256, 0, stream>>>(qn0, Kf, Vf, ctx_all + (size_t)8192 * 256,
                                                amask, 1);
  gemm_ln_mfma<<<320, 256, 0, stream>>>(ctx_all, wot, bo, hidden, 3, g1, b1, aALLf, aALLb);
  ffn_mfma<<<320, 256, 0, stream>>>(aALLb, aALLf, wit, bi, wft, bf, g2, b2,
                                    h101, h1n0, 8192);
  agg_kernel<<<64, 256, 0, stream>>>(h1n0, SEQ * E, p1_0, p2_0, Wagg, bagg, agg0);

  // ================= iteration 1 =================
  prop_ln_kernel<<<dim3(64, 2), 256, 0, stream>>>(qemb, kemb, h101, uop, iop,
                                                  Wd1, bd1, l1g, l1b, Wd2, bd2, l2g, l2b,
                                                  p1_1, p2_1);
  build_h2_kernel<<<64, 256, 0, stream>>>(qemb, kemb, demb, cemb, agg0, h1n0, h2inf, h2inb);

  qkv3_kernel<<<64, 256, 0, stream>>>(h2inb,
                                      wqt + 65536, bq + E, q2b,
                                      wkt + 65536, bk + E, k2b,
                                      wvt + 65536, bv + E, v2b);
  attnf_kernel<<<dim3(64, 4), 256, 0, stream>>>(q2b, k2b, v2b, ctx1, amask, 0);
  gemm_ln_mfma<<<64, 256, 0, stream>>>(ctx1, wot + 65536, bo + E, h2inf, 0,
                                       g1 + E, b1 + E, a2f, a2b);
  ffn_mfma<<<64, 256, 0, stream>>>(a2b, a2f, wit + 262144, bi + FF, wft + 262144, bf + E,
                                   g2 + E, b2 + E, h2, h2, 1 << 30);
  agg_kernel<<<64, 256, 0, stream>>>(h2, SEQ * E, p1_1, p2_1,
                                     Wagg + (size_t)768 * E, bagg + E, agg1);

  out_kernel<<<64, 256, 0, stream>>>(h1n0, agg0, h2, agg1, (float*)d_out);
}